// Round 5
// baseline (1492.115 us; speedup 1.0000x reference)
//
#include <hip/hip_runtime.h>

#define N_NODES 10000
#define N_EDGES 160000
#define HID 128
#define NG 100
#define NF 64
#define NIO 4096     // NF*NF (w2 row stride)
#define NJ 8192      // permuted columns: k(128) x o(64)
#define M_PAD 10240  // padded bf16-x rows (chunked GEMM may read past N_NODES)

typedef short bf16x8 __attribute__((ext_vector_type(8)));
typedef float f32x4 __attribute__((ext_vector_type(4)));

__device__ __forceinline__ unsigned short f2b(float f) {
    unsigned int u = __float_as_uint(f);
    u += 0x7fffu + ((u >> 16) & 1u);  // RNE
    return (unsigned short)(u >> 16);
}
__device__ __forceinline__ float b2f(unsigned short s) { return __uint_as_float((unsigned int)s << 16); }
__device__ __forceinline__ float b2f_lo(unsigned int u) { return __uint_as_float(u << 16); }
__device__ __forceinline__ float b2f_hi(unsigned int u) { return __uint_as_float(u & 0xffff0000u); }

// ---------------- histograms ----------------
__global__ void deg_kernel(const int* __restrict__ dst, float* __restrict__ deg) {
    int e = blockIdx.x * 256 + threadIdx.x;
    if (e < N_EDGES) atomicAdd(&deg[dst[e]], 1.0f);
}
__global__ void invdeg_kernel(const float* __restrict__ deg, float* __restrict__ invd) {
    int n = blockIdx.x * 256 + threadIdx.x;
    if (n < N_NODES) invd[n] = 1.0f / fmaxf(deg[n], 1.0f);
}
__global__ void cnt_kernel(const int* __restrict__ src, int* __restrict__ cnt) {
    int e = blockIdx.x * 256 + threadIdx.x;
    if (e < N_EDGES) atomicAdd(&cnt[src[e]], 1);
}

// ---------------- exclusive scan over cnt -> rowptr (single block) ----------------
__global__ void scan_kernel(const int* __restrict__ cnt, int* __restrict__ rowptr) {
    __shared__ int buf[256];
    __shared__ int base;
    int t = threadIdx.x;
    if (t == 0) base = 0;
    __syncthreads();
    for (int c0 = 0; c0 < N_NODES; c0 += 256) {
        int v = (c0 + t < N_NODES) ? cnt[c0 + t] : 0;
        buf[t] = v;
        __syncthreads();
        for (int off = 1; off < 256; off <<= 1) {
            int x = (t >= off) ? buf[t - off] : 0;
            __syncthreads();
            buf[t] += x;
            __syncthreads();
        }
        if (c0 + t < N_NODES) rowptr[c0 + t] = base + buf[t] - v;  // exclusive
        __syncthreads();
        if (t == 0) base += buf[255];
        __syncthreads();
    }
    if (t == 0) rowptr[N_NODES] = base;
}

// ---------------- scatter: rankOf[e], dstp[rank] ----------------
__global__ void scatter_kernel(const int* __restrict__ src, const int* __restrict__ dst,
                               const int* __restrict__ rowptr, int* __restrict__ fill,
                               int* __restrict__ rankOf, int* __restrict__ dstp) {
    int e = blockIdx.x * 256 + threadIdx.x;
    if (e < N_EDGES) {
        int s = src[e];
        int r = rowptr[s] + atomicAdd(&fill[s], 1);
        rankOf[e] = r;
        dstp[r] = dst[e];
    }
}

// ---------------- x0 = relu(h @ lin0_w + b); f32 + split-bf16 mirrors ----------------
__global__ void lin0_kernel(const float* __restrict__ h, const float* __restrict__ w,
                            const float* __restrict__ b, float* __restrict__ x,
                            unsigned short* __restrict__ xh, unsigned short* __restrict__ xl) {
    int wv = threadIdx.x >> 6, l = threadIdx.x & 63;
    int n = blockIdx.x * 4 + wv;
    float h0 = h[n * HID + l];
    float h1 = h[n * HID + 64 + l];
    float acc = b[l];
#pragma unroll
    for (int i = 0; i < 64; ++i) {
        acc += __shfl(h0, i) * w[i * NF + l];
        acc += __shfl(h1, i) * w[(64 + i) * NF + l];
    }
    float v = fmaxf(acc, 0.0f);
    x[n * NF + l] = v;
    unsigned short hi = f2b(v);
    xh[n * NF + l] = hi;
    xl[n * NF + l] = f2b(v - b2f(hi));
}

// ---------------- hidden = relu(edge_attr @ w1 + b1), bf16, written at rank position ----------------
__global__ void hidden_kernel(const float* __restrict__ ea, const float* __restrict__ w1,
                              const float* __restrict__ b1, const int* __restrict__ rankOf,
                              unsigned short* __restrict__ hidp) {
    __shared__ float ealds[2][NG];
    int sub = threadIdx.x >> 7, c = threadIdx.x & 127;
    int t = threadIdx.x;
    long e = (long)blockIdx.x * 2 + sub;
    if (t < 2 * NG) ealds[t / NG][t % NG] = ea[(long)blockIdx.x * 2 * NG + t];
    __syncthreads();
    float acc = b1[c];
#pragma unroll
    for (int k = 0; k < NG; ++k) acc += ealds[sub][k] * w1[k * HID + c];
    long r = rankOf[e];
    hidp[r * HID + c] = f2b(fmaxf(acc, 0.0f));
}

// ---------------- w2pt[j*64+i] = split-bf16(w2[k(j)*4096 + i*64 + o(j)]), j=k*64+o ----------------
__global__ void w2pt_kernel(const float* __restrict__ w2, unsigned short* __restrict__ wh,
                            unsigned short* __restrict__ wl) {
    int id = blockIdx.x * 256 + threadIdx.x;  // id = j*64 + i, over NJ*64
    int i = id & 63, j = id >> 6;
    int k = j >> 6, o = j & 63;
    float v = w2[k * NIO + i * 64 + o];
    unsigned short hi = f2b(v);
    wh[id] = hi;
    wl[id] = f2b(v - b2f(hi));
}

// ---------------- xb2[n,o] = sum_i x[n,i] * b2[i*64+o]  (f32, exact) ----------------
__global__ void xb2_kernel(const float* __restrict__ x, const float* __restrict__ b2,
                           float* __restrict__ xb2) {
    int wv = threadIdx.x >> 6, l = threadIdx.x & 63;
    int n = blockIdx.x * 4 + wv;
    float xv = x[n * NF + l];
    float acc = 0.0f;
#pragma unroll
    for (int i = 0; i < 64; ++i) acc += __shfl(xv, i) * b2[i * 64 + l];
    xb2[n * NF + l] = acc;
}

// ---------------- y[r, j] = sum_i x[n0+r, i] * w2p[j, i]  (split-bf16 3-pass MFMA) ----------------
__launch_bounds__(256)
__global__ void ygemm_kernel(const unsigned short* __restrict__ xh, const unsigned short* __restrict__ xl,
                             const unsigned short* __restrict__ wh, const unsigned short* __restrict__ wl,
                             unsigned short* __restrict__ y, int n0) {
    __shared__ float stg[4][1024];  // per-wave private 4KB staging
    const int tid = threadIdx.x, wv = tid >> 6, l = tid & 63;
    const int grow = blockIdx.x * 128;  // chunk-local row base
    const int col0 = blockIdx.y * 128;  // in [0, 8192)
    const int wr = (wv >> 1) * 64, wc = (wv & 1) * 64;
    const long aoff = (long)(n0 + grow) * NF;
    const long boff = (long)col0 * NF;

    f32x4 acc[4][4] = {};
#pragma unroll
    for (int ks = 0; ks < 2; ++ks) {
        bf16x8 ah[4], al[4], bh[4], bl[4];
#pragma unroll
        for (int m = 0; m < 4; ++m) {
            long o = aoff + (wr + m * 16 + (l & 15)) * NF + ks * 32 + (l >> 4) * 8;
            ah[m] = *(const bf16x8*)(xh + o);
            al[m] = *(const bf16x8*)(xl + o);
        }
#pragma unroll
        for (int n = 0; n < 4; ++n) {
            long o = boff + (wc + n * 16 + (l & 15)) * NF + ks * 32 + (l >> 4) * 8;
            bh[n] = *(const bf16x8*)(wh + o);
            bl[n] = *(const bf16x8*)(wl + o);
        }
#pragma unroll
        for (int m = 0; m < 4; ++m)
#pragma unroll
            for (int n = 0; n < 4; ++n) {
                acc[m][n] = __builtin_amdgcn_mfma_f32_16x16x32_bf16(ah[m], bh[n], acc[m][n], 0, 0, 0);
                acc[m][n] = __builtin_amdgcn_mfma_f32_16x16x32_bf16(ah[m], bl[n], acc[m][n], 0, 0, 0);
                acc[m][n] = __builtin_amdgcn_mfma_f32_16x16x32_bf16(al[m], bh[n], acc[m][n], 0, 0, 0);
            }
    }

    float* s = stg[wv];
    int r8 = l >> 3, cg = l & 7;
#pragma unroll
    for (int m = 0; m < 4; ++m) {
#pragma unroll
        for (int n = 0; n < 4; ++n)
#pragma unroll
            for (int q = 0; q < 4; ++q)
                s[((l >> 4) * 4 + q) * 64 + n * 16 + (l & 15)] = acc[m][n][q];
        // wave-private staging: same-wave ds_write -> ds_read ordered via lgkmcnt
#pragma unroll
        for (int it = 0; it < 2; ++it) {
            int row = it * 8 + r8;
            const float* sr = s + row * 64 + cg * 8;
            unsigned int u[4];
#pragma unroll
            for (int p = 0; p < 4; ++p)
                u[p] = ((unsigned int)f2b(sr[2 * p + 1]) << 16) | f2b(sr[2 * p]);
            long R = grow + wr + m * 16 + row;  // chunk-local
            *(uint4*)(y + R * NJ + col0 + wc + cg * 8) = make_uint4(u[0], u[1], u[2], u[3]);
        }
    }
}

// ---------------- CSR matvec: block = source node; 4 waves walk its edge ranks ----------------
__global__ void matvec_csr_kernel(const unsigned short* __restrict__ y,
                                  const unsigned short* __restrict__ hidp,
                                  const int* __restrict__ rowptr, const int* __restrict__ dstp,
                                  const float* __restrict__ xb2, float* __restrict__ agg,
                                  int n0) {
    int wv = threadIdx.x >> 6, l = threadIdx.x & 63;
    int s = n0 + blockIdx.x;
    int r0 = rowptr[s], r1 = rowptr[s + 1];
    if (r0 == r1) return;
    int r8 = l >> 3;
    int o = (l & 7) * 8 + r8;
    float xb2v = xb2[(long)s * NF + o];
    const uint4* Y = (const uint4*)(y + (long)(s - n0) * NJ);  // 16KB row, L1-hot after first wave

    for (int rank = r0 + wv; rank < r1; rank += 4) {
        float hv0 = b2f(hidp[(long)rank * HID + l]);
        float hv1 = b2f(hidp[(long)rank * HID + 64 + l]);
        float acc[8] = {0, 0, 0, 0, 0, 0, 0, 0};
#pragma unroll
        for (int t = 0; t < 16; ++t) {
            uint4 w = Y[t * 64 + l];  // covers k = 8t + r8, o = (l&7)*8 .. +8
            float hk = (t < 8) ? __shfl(hv0, r8 + 8 * t) : __shfl(hv1, r8 + 8 * t - 64);
            acc[0] += hk * b2f_lo(w.x);
            acc[1] += hk * b2f_hi(w.x);
            acc[2] += hk * b2f_lo(w.y);
            acc[3] += hk * b2f_hi(w.y);
            acc[4] += hk * b2f_lo(w.z);
            acc[5] += hk * b2f_hi(w.z);
            acc[6] += hk * b2f_lo(w.w);
            acc[7] += hk * b2f_hi(w.w);
        }
#pragma unroll
        for (int t = 0; t < 8; ++t) {
            acc[t] += __shfl_xor(acc[t], 8);
            acc[t] += __shfl_xor(acc[t], 16);
            acc[t] += __shfl_xor(acc[t], 32);
        }
        float v = acc[0];
        v = (r8 == 1) ? acc[1] : v;
        v = (r8 == 2) ? acc[2] : v;
        v = (r8 == 3) ? acc[3] : v;
        v = (r8 == 4) ? acc[4] : v;
        v = (r8 == 5) ? acc[5] : v;
        v = (r8 == 6) ? acc[6] : v;
        v = (r8 == 7) ? acc[7] : v;
        v += xb2v;
        atomicAdd(&agg[(long)dstp[rank] * NF + o], v);
    }
}

// ---------------- x' = agg*inv_deg + x @ root_w + conv_b (+ optional split mirrors) ----------------
__global__ void combine_kernel(const float* __restrict__ x, const float* __restrict__ agg,
                               const float* __restrict__ invd, const float* __restrict__ rw,
                               const float* __restrict__ cb, float* __restrict__ xo,
                               unsigned short* __restrict__ xh, unsigned short* __restrict__ xl) {
    int wv = threadIdx.x >> 6, l = threadIdx.x & 63;
    int n = blockIdx.x * 4 + wv;
    float xv = x[n * NF + l];
    float acc = cb[l];
#pragma unroll
    for (int i = 0; i < 64; ++i) acc += __shfl(xv, i) * rw[i * NF + l];
    float v = agg[n * NF + l] * invd[n] + acc;
    xo[n * NF + l] = v;
    if (xh) {
        unsigned short hi = f2b(v);
        xh[n * NF + l] = hi;
        xl[n * NF + l] = f2b(v - b2f(hi));
    }
}

extern "C" void kernel_launch(void* const* d_in, const int* in_sizes, int n_in,
                              void* d_out, int out_size, void* d_ws, size_t ws_size,
                              hipStream_t stream) {
    const float* h = (const float*)d_in[0];
    const int* ei = (const int*)d_in[1];  // int inputs arrive as int32
    const float* ea = (const float*)d_in[3];
    const float* lin0_w = (const float*)d_in[5];
    const float* lin0_b = (const float*)d_in[6];
    const float* nn_w1 = (const float*)d_in[7];
    const float* nn_b1 = (const float*)d_in[8];
    const float* nn_w2 = (const float*)d_in[9];
    const float* nn_b2 = (const float*)d_in[10];
    const float* root_w = (const float*)d_in[11];
    const float* conv_b = (const float*)d_in[12];
    const int* srcIdx = ei;
    const int* dstIdx = ei + N_EDGES;

    // ---- tier selection: pick fewest node-chunks whose y-buffer fits ws ----
    const size_t fixed =
        (size_t)N_EDGES * HID * 2 +      // hidp
        (size_t)NJ * NF * 2 * 2 +        // w2pt hi/lo
        (size_t)M_PAD * NF * 2 * 2 +     // x hi/lo mirrors
        (size_t)N_NODES * NF * 4 * 4 +   // xA, xB, agg, xb2
        (size_t)N_NODES * 4 * 4 +        // deg, invd, cnt, fill
        (size_t)(N_NODES + 1) * 4 +      // rowptr
        (size_t)N_EDGES * 4 * 2 +        // rankOf, dstp
        32768;                           // alignment slack
    int nc = 0, CSn = 0, CSp = 0;
    for (int c = 1; c <= 16; c *= 2) {
        int csn = (N_NODES + c - 1) / c;
        int csp = ((csn + 127) / 128) * 128;
        if (fixed + (size_t)csp * NJ * 2 <= ws_size) { nc = c; CSn = csn; CSp = csp; break; }
    }
    if (nc == 0) {
        hipMemsetAsync(d_out, 0, (size_t)out_size * 4, stream);
        return;
    }

    char* ws = (char*)d_ws;
    size_t off = 0;
    auto alloc = [&](size_t bytes) {
        char* p = ws + off;
        off += (bytes + 255) & ~(size_t)255;
        return p;
    };
    unsigned short* y = (unsigned short*)alloc((size_t)CSp * NJ * 2);
    unsigned short* hidp = (unsigned short*)alloc((size_t)N_EDGES * HID * 2);
    unsigned short* w2h = (unsigned short*)alloc((size_t)NJ * NF * 2);
    unsigned short* w2l = (unsigned short*)alloc((size_t)NJ * NF * 2);
    unsigned short* xh = (unsigned short*)alloc((size_t)M_PAD * NF * 2);
    unsigned short* xl = (unsigned short*)alloc((size_t)M_PAD * NF * 2);
    float* xA = (float*)alloc((size_t)N_NODES * NF * 4);
    float* xB = (float*)alloc((size_t)N_NODES * NF * 4);
    float* agg = (float*)alloc((size_t)N_NODES * NF * 4);
    float* xb2 = (float*)alloc((size_t)N_NODES * NF * 4);
    float* deg = (float*)alloc((size_t)N_NODES * 4);
    float* invd = (float*)alloc((size_t)N_NODES * 4);
    int* cnt = (int*)alloc((size_t)N_NODES * 4);
    int* fill = (int*)alloc((size_t)N_NODES * 4);
    int* rowptr = (int*)alloc((size_t)(N_NODES + 1) * 4);
    int* rankOf = (int*)alloc((size_t)N_EDGES * 4);
    int* dstp = (int*)alloc((size_t)N_EDGES * 4);

    // ---- CSR by src + prep ----
    hipMemsetAsync(deg, 0, (size_t)N_NODES * 4, stream);
    hipMemsetAsync(cnt, 0, (size_t)N_NODES * 4, stream);
    hipMemsetAsync(fill, 0, (size_t)N_NODES * 4, stream);
    deg_kernel<<<(N_EDGES + 255) / 256, 256, 0, stream>>>(dstIdx, deg);
    invdeg_kernel<<<(N_NODES + 255) / 256, 256, 0, stream>>>(deg, invd);
    cnt_kernel<<<(N_EDGES + 255) / 256, 256, 0, stream>>>(srcIdx, cnt);
    scan_kernel<<<1, 256, 0, stream>>>(cnt, rowptr);
    scatter_kernel<<<(N_EDGES + 255) / 256, 256, 0, stream>>>(srcIdx, dstIdx, rowptr, fill, rankOf, dstp);
    lin0_kernel<<<N_NODES / 4, 256, 0, stream>>>(h, lin0_w, lin0_b, xA, xh, xl);
    hidden_kernel<<<N_EDGES / 2, 256, 0, stream>>>(ea, nn_w1, nn_b1, rankOf, hidp);
    w2pt_kernel<<<(NJ * NF) / 256, 256, 0, stream>>>(nn_w2, w2h, w2l);

    // ---- two conv applications (shared weights) ----
    for (int conv = 0; conv < 2; ++conv) {
        const float* xin = conv ? xB : xA;
        float* xout = conv ? (float*)d_out : xB;
        unsigned short* mh = conv ? nullptr : xh;
        unsigned short* ml = conv ? nullptr : xl;

        xb2_kernel<<<N_NODES / 4, 256, 0, stream>>>(xin, nn_b2, xb2);
        hipMemsetAsync(agg, 0, (size_t)N_NODES * NF * 4, stream);
        for (int c = 0; c < nc; ++c) {
            int n0 = c * CSn;
            int n1 = n0 + CSn; if (n1 > N_NODES) n1 = N_NODES;
            if (n0 >= N_NODES) break;
            int gx = (n1 - n0 + 127) / 128;
            ygemm_kernel<<<dim3(gx, 64), 256, 0, stream>>>(xh, xl, w2h, w2l, y, n0);
            matvec_csr_kernel<<<n1 - n0, 256, 0, stream>>>(y, hidp, rowptr, dstp, xb2, agg, n0);
        }
        combine_kernel<<<N_NODES / 4, 256, 0, stream>>>(xin, agg, invd, root_w, conv_b, xout, mh, ml);
    }
}

// Round 6
// 700.352 us; speedup vs baseline: 2.1305x; 2.1305x over previous
//
#include <hip/hip_runtime.h>

#define N_NODES 10000
#define N_EDGES 160000
#define HID 128
#define NG 100
#define NF 64
#define NIO 4096     // NF*NF (w2 row stride)
#define NJ 8192      // permuted columns: o(64) x k(128), o-major
#define M_PAD 10240  // padded bf16-x rows (chunked GEMM may read past N_NODES)

typedef short bf16x8 __attribute__((ext_vector_type(8)));
typedef float f32x4 __attribute__((ext_vector_type(4)));

__device__ __forceinline__ unsigned short f2b(float f) {
    unsigned int u = __float_as_uint(f);
    u += 0x7fffu + ((u >> 16) & 1u);  // RNE
    return (unsigned short)(u >> 16);
}
__device__ __forceinline__ float b2f(unsigned short s) { return __uint_as_float((unsigned int)s << 16); }

// ---------------- histograms (dst-degree for mean; src-count for CSR) ----------------
__global__ void hist_kernel(const int* __restrict__ src, const int* __restrict__ dst,
                            float* __restrict__ deg, int* __restrict__ cnt) {
    int e = blockIdx.x * 256 + threadIdx.x;
    if (e < N_EDGES) {
        atomicAdd(&deg[dst[e]], 1.0f);
        atomicAdd(&cnt[src[e]], 1);
    }
}
__global__ void invdeg_kernel(const float* __restrict__ deg, float* __restrict__ invd) {
    int n = blockIdx.x * 256 + threadIdx.x;
    if (n < N_NODES) invd[n] = 1.0f / fmaxf(deg[n], 1.0f);
}

// ---------------- exclusive scan over cnt -> rowptr (single block) ----------------
__global__ void scan_kernel(const int* __restrict__ cnt, int* __restrict__ rowptr) {
    __shared__ int buf[256];
    __shared__ int base;
    int t = threadIdx.x;
    if (t == 0) base = 0;
    __syncthreads();
    for (int c0 = 0; c0 < N_NODES; c0 += 256) {
        int v = (c0 + t < N_NODES) ? cnt[c0 + t] : 0;
        buf[t] = v;
        __syncthreads();
        for (int off = 1; off < 256; off <<= 1) {
            int x = (t >= off) ? buf[t - off] : 0;
            __syncthreads();
            buf[t] += x;
            __syncthreads();
        }
        if (c0 + t < N_NODES) rowptr[c0 + t] = base + buf[t] - v;  // exclusive
        __syncthreads();
        if (t == 0) base += buf[255];
        __syncthreads();
    }
    if (t == 0) rowptr[N_NODES] = base;
}

// ---------------- scatter: rankOf[e], dstp[rank] ----------------
__global__ void scatter_kernel(const int* __restrict__ src, const int* __restrict__ dst,
                               const int* __restrict__ rowptr, int* __restrict__ fill,
                               int* __restrict__ rankOf, int* __restrict__ dstp) {
    int e = blockIdx.x * 256 + threadIdx.x;
    if (e < N_EDGES) {
        int s = src[e];
        int r = rowptr[s] + atomicAdd(&fill[s], 1);
        rankOf[e] = r;
        dstp[r] = dst[e];
    }
}

// ---------------- x0 = relu(h @ lin0_w + b); f32 + split-bf16 mirrors ----------------
__global__ void lin0_kernel(const float* __restrict__ h, const float* __restrict__ w,
                            const float* __restrict__ b, float* __restrict__ x,
                            unsigned short* __restrict__ xh, unsigned short* __restrict__ xl) {
    int wv = threadIdx.x >> 6, l = threadIdx.x & 63;
    int n = blockIdx.x * 4 + wv;
    float h0 = h[n * HID + l];
    float h1 = h[n * HID + 64 + l];
    float acc = b[l];
#pragma unroll
    for (int i = 0; i < 64; ++i) {
        acc += __shfl(h0, i) * w[i * NF + l];
        acc += __shfl(h1, i) * w[(64 + i) * NF + l];
    }
    float v = fmaxf(acc, 0.0f);
    x[n * NF + l] = v;
    unsigned short hi = f2b(v);
    xh[n * NF + l] = hi;
    xl[n * NF + l] = f2b(v - b2f(hi));
}

// ---------------- hidden = relu(edge_attr @ w1 + b1), bf16, written at rank position ----------------
__global__ void hidden_kernel(const float* __restrict__ ea, const float* __restrict__ w1,
                              const float* __restrict__ b1, const int* __restrict__ rankOf,
                              unsigned short* __restrict__ hidp) {
    __shared__ float ealds[2][NG];
    int sub = threadIdx.x >> 7, c = threadIdx.x & 127;
    int t = threadIdx.x;
    long e = (long)blockIdx.x * 2 + sub;
    if (t < 2 * NG) ealds[t / NG][t % NG] = ea[(long)blockIdx.x * 2 * NG + t];
    __syncthreads();
    float acc = b1[c];
#pragma unroll
    for (int k = 0; k < NG; ++k) acc += ealds[sub][k] * w1[k * HID + c];
    long r = rankOf[e];
    hidp[r * HID + c] = f2b(fmaxf(acc, 0.0f));
}

// ---------------- w2pt[j*64+i] = split-bf16(w2[k*4096 + i*64 + o]), j = o*128 + k (o-major) ----------------
__global__ void w2pt_kernel(const float* __restrict__ w2, unsigned short* __restrict__ wh,
                            unsigned short* __restrict__ wl) {
    int id = blockIdx.x * 256 + threadIdx.x;  // id = j*64 + i, over NJ*64
    int i = id & 63, j = id >> 6;
    int o = j >> 7, k = j & 127;              // o in [0,64), k in [0,128)
    float v = w2[k * NIO + i * 64 + o];
    unsigned short hi = f2b(v);
    wh[id] = hi;
    wl[id] = f2b(v - b2f(hi));
}

// ---------------- xb2[n,o] = sum_i x[n,i] * b2[i*64+o]  (f32, exact) ----------------
__global__ void xb2_kernel(const float* __restrict__ x, const float* __restrict__ b2,
                           float* __restrict__ xb2) {
    int wv = threadIdx.x >> 6, l = threadIdx.x & 63;
    int n = blockIdx.x * 4 + wv;
    float xv = x[n * NF + l];
    float acc = 0.0f;
#pragma unroll
    for (int i = 0; i < 64; ++i) acc += __shfl(xv, i) * b2[i * 64 + l];
    xb2[n * NF + l] = acc;
}

// ---------------- y[r, j] = sum_i x[n0+r, i] * w2p[j, i]  (split-bf16 3-pass MFMA) ----------------
__launch_bounds__(256)
__global__ void ygemm_kernel(const unsigned short* __restrict__ xh, const unsigned short* __restrict__ xl,
                             const unsigned short* __restrict__ wh, const unsigned short* __restrict__ wl,
                             unsigned short* __restrict__ y, int n0) {
    __shared__ float stg[4][1024];  // per-wave private 4KB staging
    const int tid = threadIdx.x, wv = tid >> 6, l = tid & 63;
    const int grow = blockIdx.x * 128;  // chunk-local row base
    const int col0 = blockIdx.y * 128;  // in [0, NJ)
    const int wr = (wv >> 1) * 64, wc = (wv & 1) * 64;
    const long aoff = (long)(n0 + grow) * NF;
    const long boff = (long)col0 * NF;

    f32x4 acc[4][4] = {};
#pragma unroll
    for (int ks = 0; ks < 2; ++ks) {
        bf16x8 ah[4], al[4], bh[4], bl[4];
#pragma unroll
        for (int m = 0; m < 4; ++m) {
            long o = aoff + (wr + m * 16 + (l & 15)) * NF + ks * 32 + (l >> 4) * 8;
            ah[m] = *(const bf16x8*)(xh + o);
            al[m] = *(const bf16x8*)(xl + o);
        }
#pragma unroll
        for (int n = 0; n < 4; ++n) {
            long o = boff + (wc + n * 16 + (l & 15)) * NF + ks * 32 + (l >> 4) * 8;
            bh[n] = *(const bf16x8*)(wh + o);
            bl[n] = *(const bf16x8*)(wl + o);
        }
#pragma unroll
        for (int m = 0; m < 4; ++m)
#pragma unroll
            for (int n = 0; n < 4; ++n) {
                acc[m][n] = __builtin_amdgcn_mfma_f32_16x16x32_bf16(ah[m], bh[n], acc[m][n], 0, 0, 0);
                acc[m][n] = __builtin_amdgcn_mfma_f32_16x16x32_bf16(ah[m], bl[n], acc[m][n], 0, 0, 0);
                acc[m][n] = __builtin_amdgcn_mfma_f32_16x16x32_bf16(al[m], bh[n], acc[m][n], 0, 0, 0);
            }
    }

    float* s = stg[wv];
    int r8 = l >> 3, cg = l & 7;
#pragma unroll
    for (int m = 0; m < 4; ++m) {
#pragma unroll
        for (int n = 0; n < 4; ++n)
#pragma unroll
            for (int q = 0; q < 4; ++q)
                s[((l >> 4) * 4 + q) * 64 + n * 16 + (l & 15)] = acc[m][n][q];
        // wave-private staging: same-wave ds_write -> ds_read ordered via lgkmcnt
#pragma unroll
        for (int it = 0; it < 2; ++it) {
            int row = it * 8 + r8;
            const float* sr = s + row * 64 + cg * 8;
            unsigned int u[4];
#pragma unroll
            for (int p = 0; p < 4; ++p)
                u[p] = ((unsigned int)f2b(sr[2 * p + 1]) << 16) | f2b(sr[2 * p]);
            long R = grow + wr + m * 16 + row;  // chunk-local
            *(uint4*)(y + R * NJ + col0 + wc + cg * 8) = make_uint4(u[0], u[1], u[2], u[3]);
        }
    }
}

// ---------------- per-node MFMA matvec: msg[d x 64] = H_s[d x 128] @ Y_s[128 x 64] ----------------
// block = source node; wave wv handles o-quadrant [wv*16, wv*16+16)
__global__ void matvec_mfma_kernel(const unsigned short* __restrict__ y,
                                   const unsigned short* __restrict__ hidp,
                                   const int* __restrict__ rowptr, const int* __restrict__ dstp,
                                   const float* __restrict__ xb2, float* __restrict__ agg,
                                   int n0) {
    int wv = threadIdx.x >> 6, l = threadIdx.x & 63;
    int s = n0 + blockIdx.x;
    int r0 = rowptr[s], r1 = rowptr[s + 1];
    if (r0 == r1) return;
    int co = wv * 16;              // o-quadrant base
    int lc = l & 15, lk = l >> 4;  // fragment col / k-group

    // B-fragments: Y_s stored o-major [o][k], k contiguous -> bf16x8 per (ks)
    const unsigned short* Ys = y + (long)(s - n0) * NJ + (co + lc) * HID;
    bf16x8 b[4];
#pragma unroll
    for (int ks = 0; ks < 4; ++ks) b[ks] = *(const bf16x8*)(Ys + ks * 32 + lk * 8);
    float xb2v = xb2[(long)s * NF + co + lc];

    for (int mt = r0; mt < r1; mt += 16) {
        const unsigned short* Hs = hidp + (long)(mt + lc) * HID + lk * 8;
        f32x4 acc = {};
#pragma unroll
        for (int ks = 0; ks < 4; ++ks) {
            bf16x8 a = *(const bf16x8*)(Hs + ks * 32);  // rows beyond r1: padded garbage, discarded below
            acc = __builtin_amdgcn_mfma_f32_16x16x32_bf16(a, b[ks], acc, 0, 0, 0);
        }
#pragma unroll
        for (int q = 0; q < 4; ++q) {
            int rank = mt + lk * 4 + q;  // C row = (l>>4)*4 + q
            if (rank < r1) {
                int dd = dstp[rank];
                atomicAdd(&agg[(long)dd * NF + co + lc], acc[q] + xb2v);
            }
        }
    }
}

// ---------------- x' = agg*inv_deg + x @ root_w + conv_b (+ optional split mirrors) ----------------
__global__ void combine_kernel(const float* __restrict__ x, const float* __restrict__ agg,
                               const float* __restrict__ invd, const float* __restrict__ rw,
                               const float* __restrict__ cb, float* __restrict__ xo,
                               unsigned short* __restrict__ xh, unsigned short* __restrict__ xl) {
    int wv = threadIdx.x >> 6, l = threadIdx.x & 63;
    int n = blockIdx.x * 4 + wv;
    float xv = x[n * NF + l];
    float acc = cb[l];
#pragma unroll
    for (int i = 0; i < 64; ++i) acc += __shfl(xv, i) * rw[i * NF + l];
    float v = agg[n * NF + l] * invd[n] + acc;
    xo[n * NF + l] = v;
    if (xh) {
        unsigned short hi = f2b(v);
        xh[n * NF + l] = hi;
        xl[n * NF + l] = f2b(v - b2f(hi));
    }
}

extern "C" void kernel_launch(void* const* d_in, const int* in_sizes, int n_in,
                              void* d_out, int out_size, void* d_ws, size_t ws_size,
                              hipStream_t stream) {
    const float* h = (const float*)d_in[0];
    const int* ei = (const int*)d_in[1];  // int inputs arrive as int32
    const float* ea = (const float*)d_in[3];
    const float* lin0_w = (const float*)d_in[5];
    const float* lin0_b = (const float*)d_in[6];
    const float* nn_w1 = (const float*)d_in[7];
    const float* nn_b1 = (const float*)d_in[8];
    const float* nn_w2 = (const float*)d_in[9];
    const float* nn_b2 = (const float*)d_in[10];
    const float* root_w = (const float*)d_in[11];
    const float* conv_b = (const float*)d_in[12];
    const int* srcIdx = ei;
    const int* dstIdx = ei + N_EDGES;

    // ---- tier selection: pick fewest node-chunks whose y-buffer fits ws ----
    const size_t fixed =
        (size_t)(N_EDGES + 16) * HID * 2 +  // hidp (+16 pad rows for MFMA tail over-read)
        (size_t)NJ * NF * 2 * 2 +           // w2pt hi/lo
        (size_t)M_PAD * NF * 2 * 2 +        // x hi/lo mirrors
        (size_t)N_NODES * NF * 4 * 4 +      // xA, xB, agg, xb2
        (size_t)N_NODES * 4 * 4 +           // deg, invd, cnt, fill
        (size_t)(N_NODES + 1) * 4 +         // rowptr
        (size_t)N_EDGES * 4 * 2 +           // rankOf, dstp
        32768;                              // alignment slack
    int nc = 0, CSn = 0, CSp = 0;
    for (int c = 1; c <= 16; c *= 2) {
        int csn = (N_NODES + c - 1) / c;
        int csp = ((csn + 127) / 128) * 128;
        if (fixed + (size_t)csp * NJ * 2 <= ws_size) { nc = c; CSn = csn; CSp = csp; break; }
    }
    if (nc == 0) {
        hipMemsetAsync(d_out, 0, (size_t)out_size * 4, stream);
        return;
    }

    char* ws = (char*)d_ws;
    size_t off = 0;
    auto alloc = [&](size_t bytes) {
        char* p = ws + off;
        off += (bytes + 255) & ~(size_t)255;
        return p;
    };
    unsigned short* y = (unsigned short*)alloc((size_t)CSp * NJ * 2);
    unsigned short* hidp = (unsigned short*)alloc((size_t)(N_EDGES + 16) * HID * 2);
    unsigned short* w2h = (unsigned short*)alloc((size_t)NJ * NF * 2);
    unsigned short* w2l = (unsigned short*)alloc((size_t)NJ * NF * 2);
    unsigned short* xh = (unsigned short*)alloc((size_t)M_PAD * NF * 2);
    unsigned short* xl = (unsigned short*)alloc((size_t)M_PAD * NF * 2);
    float* xA = (float*)alloc((size_t)N_NODES * NF * 4);
    float* xB = (float*)alloc((size_t)N_NODES * NF * 4);
    float* agg = (float*)alloc((size_t)N_NODES * NF * 4);
    float* xb2 = (float*)alloc((size_t)N_NODES * NF * 4);
    float* deg = (float*)alloc((size_t)N_NODES * 4);
    float* invd = (float*)alloc((size_t)N_NODES * 4);
    int* cnt = (int*)alloc((size_t)N_NODES * 4);
    int* fill = (int*)alloc((size_t)N_NODES * 4);
    int* rowptr = (int*)alloc((size_t)(N_NODES + 1) * 4);
    int* rankOf = (int*)alloc((size_t)N_EDGES * 4);
    int* dstp = (int*)alloc((size_t)N_EDGES * 4);

    // ---- CSR by src + prep ----
    hipMemsetAsync(deg, 0, (size_t)N_NODES * 4, stream);
    hipMemsetAsync(cnt, 0, (size_t)N_NODES * 4, stream);
    hipMemsetAsync(fill, 0, (size_t)N_NODES * 4, stream);
    hist_kernel<<<(N_EDGES + 255) / 256, 256, 0, stream>>>(srcIdx, dstIdx, deg, cnt);
    invdeg_kernel<<<(N_NODES + 255) / 256, 256, 0, stream>>>(deg, invd);
    scan_kernel<<<1, 256, 0, stream>>>(cnt, rowptr);
    scatter_kernel<<<(N_EDGES + 255) / 256, 256, 0, stream>>>(srcIdx, dstIdx, rowptr, fill, rankOf, dstp);
    lin0_kernel<<<N_NODES / 4, 256, 0, stream>>>(h, lin0_w, lin0_b, xA, xh, xl);
    hidden_kernel<<<N_EDGES / 2, 256, 0, stream>>>(ea, nn_w1, nn_b1, rankOf, hidp);
    w2pt_kernel<<<(NJ * NF) / 256, 256, 0, stream>>>(nn_w2, w2h, w2l);

    // ---- two conv applications (shared weights) ----
    for (int conv = 0; conv < 2; ++conv) {
        const float* xin = conv ? xB : xA;
        float* xout = conv ? (float*)d_out : xB;
        unsigned short* mh = conv ? nullptr : xh;
        unsigned short* ml = conv ? nullptr : xl;

        xb2_kernel<<<N_NODES / 4, 256, 0, stream>>>(xin, nn_b2, xb2);
        hipMemsetAsync(agg, 0, (size_t)N_NODES * NF * 4, stream);
        for (int c = 0; c < nc; ++c) {
            int n0 = c * CSn;
            int n1 = n0 + CSn; if (n1 > N_NODES) n1 = N_NODES;
            if (n0 >= N_NODES) break;
            int gx = (n1 - n0 + 127) / 128;
            ygemm_kernel<<<dim3(gx, NJ / 128), 256, 0, stream>>>(xh, xl, w2h, w2l, y, n0);
            matvec_mfma_kernel<<<n1 - n0, 256, 0, stream>>>(y, hidp, rowptr, dstp, xb2, agg, n0);
        }
        combine_kernel<<<N_NODES / 4, 256, 0, stream>>>(xin, agg, invd, root_w, conv_b, xout, mh, ml);
    }
}

// Round 7
// 567.819 us; speedup vs baseline: 2.6278x; 1.2334x over previous
//
#include <hip/hip_runtime.h>

#define N_NODES 10000
#define N_EDGES 160000
#define HID 128
#define NG 100
#define NF 64
#define NIO 4096     // NF*NF (w2 row stride)
#define NJ 8192      // permuted columns: o(64) x k(128), o-major
#define M_PAD 10240  // padded bf16-x rows (chunked GEMM may read past N_NODES)

typedef short bf16x8 __attribute__((ext_vector_type(8)));
typedef float f32x4 __attribute__((ext_vector_type(4)));

__device__ __forceinline__ unsigned short f2b(float f) {
    unsigned int u = __float_as_uint(f);
    u += 0x7fffu + ((u >> 16) & 1u);  // RNE
    return (unsigned short)(u >> 16);
}
__device__ __forceinline__ float b2f(unsigned short s) { return __uint_as_float((unsigned int)s << 16); }

// ---------------- histograms (dst-degree for mean; src-count for CSR) ----------------
__global__ void hist_kernel(const int* __restrict__ src, const int* __restrict__ dst,
                            float* __restrict__ deg, int* __restrict__ cnt) {
    int e = blockIdx.x * 256 + threadIdx.x;
    if (e < N_EDGES) {
        atomicAdd(&deg[dst[e]], 1.0f);
        atomicAdd(&cnt[src[e]], 1);
    }
}
__global__ void invdeg_kernel(const float* __restrict__ deg, float* __restrict__ invd) {
    int n = blockIdx.x * 256 + threadIdx.x;
    if (n < N_NODES) invd[n] = 1.0f / fmaxf(deg[n], 1.0f);
}

// ---------------- exclusive scan over cnt -> rowptr (single block) ----------------
__global__ void scan_kernel(const int* __restrict__ cnt, int* __restrict__ rowptr) {
    __shared__ int buf[256];
    __shared__ int base;
    int t = threadIdx.x;
    if (t == 0) base = 0;
    __syncthreads();
    for (int c0 = 0; c0 < N_NODES; c0 += 256) {
        int v = (c0 + t < N_NODES) ? cnt[c0 + t] : 0;
        buf[t] = v;
        __syncthreads();
        for (int off = 1; off < 256; off <<= 1) {
            int x = (t >= off) ? buf[t - off] : 0;
            __syncthreads();
            buf[t] += x;
            __syncthreads();
        }
        if (c0 + t < N_NODES) rowptr[c0 + t] = base + buf[t] - v;  // exclusive
        __syncthreads();
        if (t == 0) base += buf[255];
        __syncthreads();
    }
    if (t == 0) rowptr[N_NODES] = base;
}

// ---------------- scatter: rankOf[e], dstp[rank], edgeOf[rank] ----------------
__global__ void scatter_kernel(const int* __restrict__ src, const int* __restrict__ dst,
                               const int* __restrict__ rowptr, int* __restrict__ fill,
                               int* __restrict__ rankOf, int* __restrict__ dstp,
                               int* __restrict__ edgeOf) {
    int e = blockIdx.x * 256 + threadIdx.x;
    if (e < N_EDGES) {
        int s = src[e];
        int r = rowptr[s] + atomicAdd(&fill[s], 1);
        rankOf[e] = r;
        dstp[r] = dst[e];
        edgeOf[r] = e;
    }
}

// ---------------- x0 = relu(h @ lin0_w + b); f32 + split-bf16 mirrors ----------------
__global__ void lin0_kernel(const float* __restrict__ h, const float* __restrict__ w,
                            const float* __restrict__ b, float* __restrict__ x,
                            unsigned short* __restrict__ xh, unsigned short* __restrict__ xl) {
    int wv = threadIdx.x >> 6, l = threadIdx.x & 63;
    int n = blockIdx.x * 4 + wv;
    float h0 = h[n * HID + l];
    float h1 = h[n * HID + 64 + l];
    float acc = b[l];
#pragma unroll
    for (int i = 0; i < 64; ++i) {
        acc += __shfl(h0, i) * w[i * NF + l];
        acc += __shfl(h1, i) * w[(64 + i) * NF + l];
    }
    float v = fmaxf(acc, 0.0f);
    x[n * NF + l] = v;
    unsigned short hi = f2b(v);
    xh[n * NF + l] = hi;
    xl[n * NF + l] = f2b(v - b2f(hi));
}

// ---------------- eaperm: ea rows gathered to rank order, split-bf16, K padded to 128 ----------------
__global__ void eaperm_kernel(const float* __restrict__ ea, const int* __restrict__ edgeOf,
                              unsigned short* __restrict__ eah, unsigned short* __restrict__ eal) {
    int sub = threadIdx.x >> 7, c = threadIdx.x & 127;
    long r = (long)blockIdx.x * 2 + sub;
    long e = edgeOf[r];
    float v = (c < NG) ? ea[e * NG + c] : 0.0f;
    unsigned short hi = f2b(v);
    eah[r * HID + c] = hi;
    eal[r * HID + c] = f2b(v - b2f(hi));
}

// ---------------- w1pt[c*128+k] = split-bf16(w1[k*128+c]), k padded to 128 ----------------
__global__ void w1pt_kernel(const float* __restrict__ w1, unsigned short* __restrict__ wh,
                            unsigned short* __restrict__ wl) {
    int id = blockIdx.x * 256 + threadIdx.x;  // id = c*128 + k, over 128*128
    int k = id & 127, c = id >> 7;
    float v = (k < NG) ? w1[k * HID + c] : 0.0f;
    unsigned short hi = f2b(v);
    wh[id] = hi;
    wl[id] = f2b(v - b2f(hi));
}

// ---------------- hidp = relu(eap @ w1 + b1): M=NE, N=128, K=128, split-bf16 3-pass ----------------
__launch_bounds__(256)
__global__ void hgemm_kernel(const unsigned short* __restrict__ eah, const unsigned short* __restrict__ eal,
                             const unsigned short* __restrict__ w1h, const unsigned short* __restrict__ w1l,
                             const float* __restrict__ b1, unsigned short* __restrict__ hidp) {
    __shared__ float stg[4][1024];
    const int tid = threadIdx.x, wv = tid >> 6, l = tid & 63;
    const long grow = (long)blockIdx.x * 128;
    const int wr = (wv >> 1) * 64, wc = (wv & 1) * 64;
    const long aoff = grow * HID;

    f32x4 acc[4][4] = {};
#pragma unroll
    for (int ks = 0; ks < 4; ++ks) {
        bf16x8 ah[4], al[4], bh[4], bl[4];
#pragma unroll
        for (int m = 0; m < 4; ++m) {
            long o = aoff + (wr + m * 16 + (l & 15)) * HID + ks * 32 + (l >> 4) * 8;
            ah[m] = *(const bf16x8*)(eah + o);
            al[m] = *(const bf16x8*)(eal + o);
        }
#pragma unroll
        for (int n = 0; n < 4; ++n) {
            long o = (long)(wc + n * 16 + (l & 15)) * HID + ks * 32 + (l >> 4) * 8;
            bh[n] = *(const bf16x8*)(w1h + o);
            bl[n] = *(const bf16x8*)(w1l + o);
        }
#pragma unroll
        for (int m = 0; m < 4; ++m)
#pragma unroll
            for (int n = 0; n < 4; ++n) {
                acc[m][n] = __builtin_amdgcn_mfma_f32_16x16x32_bf16(ah[m], bh[n], acc[m][n], 0, 0, 0);
                acc[m][n] = __builtin_amdgcn_mfma_f32_16x16x32_bf16(ah[m], bl[n], acc[m][n], 0, 0, 0);
                acc[m][n] = __builtin_amdgcn_mfma_f32_16x16x32_bf16(al[m], bh[n], acc[m][n], 0, 0, 0);
            }
    }

    float* s = stg[wv];
    int r8 = l >> 3, cg = l & 7;
#pragma unroll
    for (int m = 0; m < 4; ++m) {
#pragma unroll
        for (int n = 0; n < 4; ++n)
#pragma unroll
            for (int q = 0; q < 4; ++q)
                s[((l >> 4) * 4 + q) * 64 + n * 16 + (l & 15)] = acc[m][n][q];
#pragma unroll
        for (int it = 0; it < 2; ++it) {
            int row = it * 8 + r8;
            const float* sr = s + row * 64 + cg * 8;
            int colbase = wc + cg * 8;
            unsigned int u[4];
#pragma unroll
            for (int p = 0; p < 4; ++p) {
                float f0 = fmaxf(sr[2 * p] + b1[colbase + 2 * p], 0.0f);
                float f1 = fmaxf(sr[2 * p + 1] + b1[colbase + 2 * p + 1], 0.0f);
                u[p] = ((unsigned int)f2b(f1) << 16) | f2b(f0);
            }
            long R = grow + wr + m * 16 + row;
            *(uint4*)(hidp + R * HID + colbase) = make_uint4(u[0], u[1], u[2], u[3]);
        }
    }
}

// ---------------- w2pt[j*64+i] = split-bf16(w2[k*4096 + i*64 + o]), j = o*128 + k (o-major) ----------------
__global__ void w2pt_kernel(const float* __restrict__ w2, unsigned short* __restrict__ wh,
                            unsigned short* __restrict__ wl) {
    int id = blockIdx.x * 256 + threadIdx.x;  // id = j*64 + i, over NJ*64
    int i = id & 63, j = id >> 6;
    int o = j >> 7, k = j & 127;              // o in [0,64), k in [0,128)
    float v = w2[k * NIO + i * 64 + o];
    unsigned short hi = f2b(v);
    wh[id] = hi;
    wl[id] = f2b(v - b2f(hi));
}

// ---------------- xb2[n,o] = sum_i x[n,i] * b2[i*64+o]  (f32, exact) ----------------
__global__ void xb2_kernel(const float* __restrict__ x, const float* __restrict__ b2,
                           float* __restrict__ xb2) {
    int wv = threadIdx.x >> 6, l = threadIdx.x & 63;
    int n = blockIdx.x * 4 + wv;
    float xv = x[n * NF + l];
    float acc = 0.0f;
#pragma unroll
    for (int i = 0; i < 64; ++i) acc += __shfl(xv, i) * b2[i * 64 + l];
    xb2[n * NF + l] = acc;
}

// ---------------- y[r, j] = sum_i x[n0+r, i] * w2p[j, i]  (split-bf16 3-pass MFMA) ----------------
__launch_bounds__(256)
__global__ void ygemm_kernel(const unsigned short* __restrict__ xh, const unsigned short* __restrict__ xl,
                             const unsigned short* __restrict__ wh, const unsigned short* __restrict__ wl,
                             unsigned short* __restrict__ y, int n0) {
    __shared__ float stg[4][1024];  // per-wave private 4KB staging
    const int tid = threadIdx.x, wv = tid >> 6, l = tid & 63;
    const int grow = blockIdx.x * 128;  // chunk-local row base
    const int col0 = blockIdx.y * 128;  // in [0, NJ)
    const int wr = (wv >> 1) * 64, wc = (wv & 1) * 64;
    const long aoff = (long)(n0 + grow) * NF;
    const long boff = (long)col0 * NF;

    f32x4 acc[4][4] = {};
#pragma unroll
    for (int ks = 0; ks < 2; ++ks) {
        bf16x8 ah[4], al[4], bh[4], bl[4];
#pragma unroll
        for (int m = 0; m < 4; ++m) {
            long o = aoff + (wr + m * 16 + (l & 15)) * NF + ks * 32 + (l >> 4) * 8;
            ah[m] = *(const bf16x8*)(xh + o);
            al[m] = *(const bf16x8*)(xl + o);
        }
#pragma unroll
        for (int n = 0; n < 4; ++n) {
            long o = boff + (wc + n * 16 + (l & 15)) * NF + ks * 32 + (l >> 4) * 8;
            bh[n] = *(const bf16x8*)(wh + o);
            bl[n] = *(const bf16x8*)(wl + o);
        }
#pragma unroll
        for (int m = 0; m < 4; ++m)
#pragma unroll
            for (int n = 0; n < 4; ++n) {
                acc[m][n] = __builtin_amdgcn_mfma_f32_16x16x32_bf16(ah[m], bh[n], acc[m][n], 0, 0, 0);
                acc[m][n] = __builtin_amdgcn_mfma_f32_16x16x32_bf16(ah[m], bl[n], acc[m][n], 0, 0, 0);
                acc[m][n] = __builtin_amdgcn_mfma_f32_16x16x32_bf16(al[m], bh[n], acc[m][n], 0, 0, 0);
            }
    }

    float* s = stg[wv];
    int r8 = l >> 3, cg = l & 7;
#pragma unroll
    for (int m = 0; m < 4; ++m) {
#pragma unroll
        for (int n = 0; n < 4; ++n)
#pragma unroll
            for (int q = 0; q < 4; ++q)
                s[((l >> 4) * 4 + q) * 64 + n * 16 + (l & 15)] = acc[m][n][q];
        // wave-private staging: same-wave ds_write -> ds_read ordered via lgkmcnt
#pragma unroll
        for (int it = 0; it < 2; ++it) {
            int row = it * 8 + r8;
            const float* sr = s + row * 64 + cg * 8;
            unsigned int u[4];
#pragma unroll
            for (int p = 0; p < 4; ++p)
                u[p] = ((unsigned int)f2b(sr[2 * p + 1]) << 16) | f2b(sr[2 * p]);
            long R = grow + wr + m * 16 + row;  // chunk-local
            *(uint4*)(y + R * NJ + col0 + wc + cg * 8) = make_uint4(u[0], u[1], u[2], u[3]);
        }
    }
}

// ---------------- per-node MFMA matvec: msg[d x 64] = H_s[d x 128] @ Y_s[128 x 64] ----------------
// block = source node; wave wv handles o-quadrant [wv*16, wv*16+16)
__global__ void matvec_mfma_kernel(const unsigned short* __restrict__ y,
                                   const unsigned short* __restrict__ hidp,
                                   const int* __restrict__ rowptr, const int* __restrict__ dstp,
                                   const float* __restrict__ xb2, float* __restrict__ agg,
                                   int n0) {
    int wv = threadIdx.x >> 6, l = threadIdx.x & 63;
    int s = n0 + blockIdx.x;
    int r0 = rowptr[s], r1 = rowptr[s + 1];
    if (r0 == r1) return;
    int co = wv * 16;              // o-quadrant base
    int lc = l & 15, lk = l >> 4;  // fragment col / k-group

    // B-fragments: Y_s stored o-major [o][k], k contiguous -> bf16x8 per (ks)
    const unsigned short* Ys = y + (long)(s - n0) * NJ + (co + lc) * HID;
    bf16x8 b[4];
#pragma unroll
    for (int ks = 0; ks < 4; ++ks) b[ks] = *(const bf16x8*)(Ys + ks * 32 + lk * 8);
    float xb2v = xb2[(long)s * NF + co + lc];

    for (int mt = r0; mt < r1; mt += 16) {
        const unsigned short* Hs = hidp + (long)(mt + lc) * HID + lk * 8;
        f32x4 acc = {};
#pragma unroll
        for (int ks = 0; ks < 4; ++ks) {
            bf16x8 a = *(const bf16x8*)(Hs + ks * 32);  // rows beyond r1: padded garbage, discarded below
            acc = __builtin_amdgcn_mfma_f32_16x16x32_bf16(a, b[ks], acc, 0, 0, 0);
        }
#pragma unroll
        for (int q = 0; q < 4; ++q) {
            int rank = mt + lk * 4 + q;  // C row = (l>>4)*4 + q
            if (rank < r1) {
                int dd = dstp[rank];
                atomicAdd(&agg[(long)dd * NF + co + lc], acc[q] + xb2v);
            }
        }
    }
}

// ---------------- x' = agg*inv_deg + x @ root_w + conv_b (+ optional split mirrors) ----------------
__global__ void combine_kernel(const float* __restrict__ x, const float* __restrict__ agg,
                               const float* __restrict__ invd, const float* __restrict__ rw,
                               const float* __restrict__ cb, float* __restrict__ xo,
                               unsigned short* __restrict__ xh, unsigned short* __restrict__ xl) {
    int wv = threadIdx.x >> 6, l = threadIdx.x & 63;
    int n = blockIdx.x * 4 + wv;
    float xv = x[n * NF + l];
    float acc = cb[l];
#pragma unroll
    for (int i = 0; i < 64; ++i) acc += __shfl(xv, i) * rw[i * NF + l];
    float v = agg[n * NF + l] * invd[n] + acc;
    xo[n * NF + l] = v;
    if (xh) {
        unsigned short hi = f2b(v);
        xh[n * NF + l] = hi;
        xl[n * NF + l] = f2b(v - b2f(hi));
    }
}

extern "C" void kernel_launch(void* const* d_in, const int* in_sizes, int n_in,
                              void* d_out, int out_size, void* d_ws, size_t ws_size,
                              hipStream_t stream) {
    const float* h = (const float*)d_in[0];
    const int* ei = (const int*)d_in[1];  // int inputs arrive as int32
    const float* ea = (const float*)d_in[3];
    const float* lin0_w = (const float*)d_in[5];
    const float* lin0_b = (const float*)d_in[6];
    const float* nn_w1 = (const float*)d_in[7];
    const float* nn_b1 = (const float*)d_in[8];
    const float* nn_w2 = (const float*)d_in[9];
    const float* nn_b2 = (const float*)d_in[10];
    const float* root_w = (const float*)d_in[11];
    const float* conv_b = (const float*)d_in[12];
    const int* srcIdx = ei;
    const int* dstIdx = ei + N_EDGES;

    // ---- tier selection: shared region = max(y chunk, ea split buffers) ----
    const size_t eaBytes = (size_t)2 * N_EDGES * HID * 2;  // eah + eal (aliased with y)
    const size_t fixed =
        (size_t)(N_EDGES + 16) * HID * 2 +  // hidp (+16 pad rows for MFMA tail over-read)
        (size_t)NJ * NF * 2 * 2 +           // w2pt hi/lo
        (size_t)HID * HID * 2 * 2 +         // w1pt hi/lo
        (size_t)M_PAD * NF * 2 * 2 +        // x hi/lo mirrors
        (size_t)N_NODES * NF * 4 * 4 +      // xA, xB, agg, xb2
        (size_t)N_NODES * 4 * 4 +           // deg, invd, cnt, fill
        (size_t)(N_NODES + 1) * 4 +         // rowptr
        (size_t)N_EDGES * 4 * 3 +           // rankOf, dstp, edgeOf
        32768;                              // alignment slack
    int nc = 0, CSn = 0, CSp = 0;
    size_t region_bytes = 0;
    for (int c = 1; c <= 16; c *= 2) {
        int csn = (N_NODES + c - 1) / c;
        int csp = ((csn + 127) / 128) * 128;
        size_t rb = (size_t)csp * NJ * 2;
        if (rb < eaBytes) rb = eaBytes;
        if (fixed + rb <= ws_size) { nc = c; CSn = csn; CSp = csp; region_bytes = rb; break; }
    }
    if (nc == 0) {
        hipMemsetAsync(d_out, 0, (size_t)out_size * 4, stream);
        return;
    }

    char* ws = (char*)d_ws;
    size_t off = 0;
    auto alloc = [&](size_t bytes) {
        char* p = ws + off;
        off += (bytes + 255) & ~(size_t)255;
        return p;
    };
    unsigned short* region = (unsigned short*)alloc(region_bytes);
    unsigned short* y = region;                                    // used in conv loop
    unsigned short* eah = region;                                  // used in prep only
    unsigned short* eal = region + (size_t)N_EDGES * HID;
    unsigned short* hidp = (unsigned short*)alloc((size_t)(N_EDGES + 16) * HID * 2);
    unsigned short* w2h = (unsigned short*)alloc((size_t)NJ * NF * 2);
    unsigned short* w2l = (unsigned short*)alloc((size_t)NJ * NF * 2);
    unsigned short* w1h = (unsigned short*)alloc((size_t)HID * HID * 2);
    unsigned short* w1l = (unsigned short*)alloc((size_t)HID * HID * 2);
    unsigned short* xh = (unsigned short*)alloc((size_t)M_PAD * NF * 2);
    unsigned short* xl = (unsigned short*)alloc((size_t)M_PAD * NF * 2);
    float* xA = (float*)alloc((size_t)N_NODES * NF * 4);
    float* xB = (float*)alloc((size_t)N_NODES * NF * 4);
    float* agg = (float*)alloc((size_t)N_NODES * NF * 4);
    float* xb2 = (float*)alloc((size_t)N_NODES * NF * 4);
    float* deg = (float*)alloc((size_t)N_NODES * 4);
    float* invd = (float*)alloc((size_t)N_NODES * 4);
    int* cnt = (int*)alloc((size_t)N_NODES * 4);
    int* fill = (int*)alloc((size_t)N_NODES * 4);
    int* rowptr = (int*)alloc((size_t)(N_NODES + 1) * 4);
    int* rankOf = (int*)alloc((size_t)N_EDGES * 4);
    int* dstp = (int*)alloc((size_t)N_EDGES * 4);
    int* edgeOf = (int*)alloc((size_t)N_EDGES * 4);

    // ---- CSR by src + prep ----
    hipMemsetAsync(deg, 0, (size_t)N_NODES * 4, stream);
    hipMemsetAsync(cnt, 0, (size_t)N_NODES * 4, stream);
    hipMemsetAsync(fill, 0, (size_t)N_NODES * 4, stream);
    hist_kernel<<<(N_EDGES + 255) / 256, 256, 0, stream>>>(srcIdx, dstIdx, deg, cnt);
    invdeg_kernel<<<(N_NODES + 255) / 256, 256, 0, stream>>>(deg, invd);
    scan_kernel<<<1, 256, 0, stream>>>(cnt, rowptr);
    scatter_kernel<<<(N_EDGES + 255) / 256, 256, 0, stream>>>(srcIdx, dstIdx, rowptr, fill, rankOf, dstp, edgeOf);
    lin0_kernel<<<N_NODES / 4, 256, 0, stream>>>(h, lin0_w, lin0_b, xA, xh, xl);
    eaperm_kernel<<<N_EDGES / 2, 256, 0, stream>>>(ea, edgeOf, eah, eal);
    w1pt_kernel<<<(HID * HID) / 256, 256, 0, stream>>>(nn_w1, w1h, w1l);
    hgemm_kernel<<<N_EDGES / 128, 256, 0, stream>>>(eah, eal, w1h, w1l, nn_b1, hidp);  // consumes ea region
    w2pt_kernel<<<(NJ * NF) / 256, 256, 0, stream>>>(nn_w2, w2h, w2l);

    // ---- two conv applications (shared weights) ----
    for (int conv = 0; conv < 2; ++conv) {
        const float* xin = conv ? xB : xA;
        float* xout = conv ? (float*)d_out : xB;
        unsigned short* mh = conv ? nullptr : xh;
        unsigned short* ml = conv ? nullptr : xl;

        xb2_kernel<<<N_NODES / 4, 256, 0, stream>>>(xin, nn_b2, xb2);
        hipMemsetAsync(agg, 0, (size_t)N_NODES * NF * 4, stream);
        for (int c = 0; c < nc; ++c) {
            int n0 = c * CSn;
            int n1 = n0 + CSn; if (n1 > N_NODES) n1 = N_NODES;
            if (n0 >= N_NODES) break;
            int gx = (n1 - n0 + 127) / 128;
            ygemm_kernel<<<dim3(gx, NJ / 128), 256, 0, stream>>>(xh, xl, w2h, w2l, y, n0);
            matvec_mfma_kernel<<<n1 - n0, 256, 0, stream>>>(y, hidp, rowptr, dstp, xb2, agg, n0);
        }
        combine_kernel<<<N_NODES / 4, 256, 0, stream>>>(xin, agg, invd, root_w, conv_b, xout, mh, ml);
    }
}

// Round 8
// 439.525 us; speedup vs baseline: 3.3948x; 1.2919x over previous
//
#include <hip/hip_runtime.h>

#define N_NODES 10000
#define N_EDGES 160000
#define HID 128
#define NG 100
#define NF 64
#define NIO 4096     // NF*NF (w2 row stride)
#define NJ 8192      // permuted columns: o(64) x k(128), o-major
#define M_PAD 10240  // padded x rows (chunked GEMM may read past N_NODES)

typedef short bf16x8 __attribute__((ext_vector_type(8)));
typedef float f32x4 __attribute__((ext_vector_type(4)));

__device__ __forceinline__ unsigned short f2b(float f) {
    unsigned int u = __float_as_uint(f);
    u += 0x7fffu + ((u >> 16) & 1u);  // RNE
    return (unsigned short)(u >> 16);
}
__device__ __forceinline__ float b2f(unsigned short s) { return __uint_as_float((unsigned int)s << 16); }

// fragment-major index helpers: element (row, k) of a K=64 operand matrix
// layout: [panel=row>>4][ks=k>>5][slot=((k>>3)&3)*16 + (row&15)][k&7], panel stride 1024
__device__ __forceinline__ long fidx64(int row, int k) {
    return (long)(row >> 4) * 1024 + (k >> 5) * 512 + ((((k >> 3) & 3) * 16 + (row & 15))) * 8 + (k & 7);
}
// K=128 operand matrix, panel stride 2048
__device__ __forceinline__ long fidx128(int row, int k) {
    return (long)(row >> 4) * 2048 + (k >> 5) * 512 + ((((k >> 3) & 3) * 16 + (row & 15))) * 8 + (k & 7);
}

// ---------------- histograms (dst-degree for mean; src-count for CSR) ----------------
__global__ void hist_kernel(const int* __restrict__ src, const int* __restrict__ dst,
                            float* __restrict__ deg, int* __restrict__ cnt) {
    int e = blockIdx.x * 256 + threadIdx.x;
    if (e < N_EDGES) {
        atomicAdd(&deg[dst[e]], 1.0f);
        atomicAdd(&cnt[src[e]], 1);
    }
}
__global__ void invdeg_kernel(const float* __restrict__ deg, float* __restrict__ invd) {
    int n = blockIdx.x * 256 + threadIdx.x;
    if (n < N_NODES) invd[n] = 1.0f / fmaxf(deg[n], 1.0f);
}

// ---------------- exclusive scan over cnt -> rowptr (single block) ----------------
__global__ void scan_kernel(const int* __restrict__ cnt, int* __restrict__ rowptr) {
    __shared__ int buf[256];
    __shared__ int base;
    int t = threadIdx.x;
    if (t == 0) base = 0;
    __syncthreads();
    for (int c0 = 0; c0 < N_NODES; c0 += 256) {
        int v = (c0 + t < N_NODES) ? cnt[c0 + t] : 0;
        buf[t] = v;
        __syncthreads();
        for (int off = 1; off < 256; off <<= 1) {
            int x = (t >= off) ? buf[t - off] : 0;
            __syncthreads();
            buf[t] += x;
            __syncthreads();
        }
        if (c0 + t < N_NODES) rowptr[c0 + t] = base + buf[t] - v;  // exclusive
        __syncthreads();
        if (t == 0) base += buf[255];
        __syncthreads();
    }
    if (t == 0) rowptr[N_NODES] = base;
}

// ---------------- scatter: rankOf[e], dstp[rank], edgeOf[rank] ----------------
__global__ void scatter_kernel(const int* __restrict__ src, const int* __restrict__ dst,
                               const int* __restrict__ rowptr, int* __restrict__ fill,
                               int* __restrict__ rankOf, int* __restrict__ dstp,
                               int* __restrict__ edgeOf) {
    int e = blockIdx.x * 256 + threadIdx.x;
    if (e < N_EDGES) {
        int s = src[e];
        int r = rowptr[s] + atomicAdd(&fill[s], 1);
        rankOf[e] = r;
        dstp[r] = dst[e];
        edgeOf[r] = e;
    }
}

// ---------------- x0 = relu(h @ lin0_w + b); f32 + split-bf16 fragment-major mirrors ----------------
__global__ void lin0_kernel(const float* __restrict__ h, const float* __restrict__ w,
                            const float* __restrict__ b, float* __restrict__ x,
                            unsigned short* __restrict__ xh, unsigned short* __restrict__ xl) {
    int wv = threadIdx.x >> 6, l = threadIdx.x & 63;
    int n = blockIdx.x * 4 + wv;
    float h0 = h[n * HID + l];
    float h1 = h[n * HID + 64 + l];
    float acc = b[l];
#pragma unroll
    for (int i = 0; i < 64; ++i) {
        acc += __shfl(h0, i) * w[i * NF + l];
        acc += __shfl(h1, i) * w[(64 + i) * NF + l];
    }
    float v = fmaxf(acc, 0.0f);
    x[n * NF + l] = v;
    unsigned short hi = f2b(v);
    long idx = fidx64(n, l);
    xh[idx] = hi;
    xl[idx] = f2b(v - b2f(hi));
}

// ---------------- eaperm: ea rows -> rank order, split-bf16, fragment-major (K pad 128) ----------------
// block = one 16-rank panel; thread t handles (ks,lk) chunk of rank (t&15): 8 contiguous c
__global__ void eaperm_kernel(const float* __restrict__ ea, const int* __restrict__ edgeOf,
                              unsigned short* __restrict__ eah, unsigned short* __restrict__ eal) {
    int t = threadIdx.x;
    int r15 = t & 15, ksl = t >> 4;  // ksl in [0,16)
    int ks = ksl >> 2, lk = ksl & 3;
    long rank = (long)blockIdx.x * 16 + r15;
    long e = edgeOf[rank];
    int c0 = ks * 32 + lk * 8;
    unsigned int uh[4], ul[4];
#pragma unroll
    for (int p = 0; p < 4; ++p) {
        float v0 = (c0 + 2 * p < NG) ? ea[e * NG + c0 + 2 * p] : 0.0f;
        float v1 = (c0 + 2 * p + 1 < NG) ? ea[e * NG + c0 + 2 * p + 1] : 0.0f;
        unsigned short h0 = f2b(v0), h1 = f2b(v1);
        uh[p] = ((unsigned int)h1 << 16) | h0;
        unsigned short l0 = f2b(v0 - b2f(h0)), l1 = f2b(v1 - b2f(h1));
        ul[p] = ((unsigned int)l1 << 16) | l0;
    }
    long idx = (long)blockIdx.x * 2048 + ks * 512 + (lk * 16 + r15) * 8;
    *(uint4*)(eah + idx) = make_uint4(uh[0], uh[1], uh[2], uh[3]);
    *(uint4*)(eal + idx) = make_uint4(ul[0], ul[1], ul[2], ul[3]);
}

// ---------------- w1pt: fragment-major split-bf16 of w1 (B[k][c], K pad 128) ----------------
__global__ void w1pt_kernel(const float* __restrict__ w1, unsigned short* __restrict__ wh,
                            unsigned short* __restrict__ wl) {
    int id = blockIdx.x * 256 + threadIdx.x;  // over 128*128: k = id&127, c = id>>7
    int k = id & 127, c = id >> 7;
    float v = (k < NG) ? w1[k * HID + c] : 0.0f;
    unsigned short hi = f2b(v);
    long idx = fidx128(c, k);
    wh[idx] = hi;
    wl[idx] = f2b(v - b2f(hi));
}

// ---------------- hgemm: hidp = relu(eap @ w1 + b1), M=NE N=128 K=128, split 3-pass ----------------
__launch_bounds__(256)
__global__ void hgemm_kernel(const unsigned short* __restrict__ eah, const unsigned short* __restrict__ eal,
                             const unsigned short* __restrict__ w1h, const unsigned short* __restrict__ w1l,
                             const float* __restrict__ b1, unsigned short* __restrict__ hidp) {
    __shared__ float stg[4][1056];  // 16 rows x stride 66
    const int tid = threadIdx.x, wv = tid >> 6, l = tid & 63;
    const long grow = (long)blockIdx.x * 128;
    const int wr = (wv >> 1) * 64, wc = (wv & 1) * 64;
    const long apan0 = (grow >> 4) + (wr >> 4);
    const long bpan0 = (wc >> 4);

    f32x4 acc[4][4] = {};
#pragma unroll
    for (int ks = 0; ks < 4; ++ks) {
        bf16x8 ah[4], al[4], bh[4], bl[4];
#pragma unroll
        for (int m = 0; m < 4; ++m) {
            long o = (apan0 + m) * 2048 + ks * 512 + (long)l * 8;
            ah[m] = *(const bf16x8*)(eah + o);
            al[m] = *(const bf16x8*)(eal + o);
        }
#pragma unroll
        for (int n = 0; n < 4; ++n) {
            long o = (bpan0 + n) * 2048 + ks * 512 + (long)l * 8;
            bh[n] = *(const bf16x8*)(w1h + o);
            bl[n] = *(const bf16x8*)(w1l + o);
        }
#pragma unroll
        for (int m = 0; m < 4; ++m)
#pragma unroll
            for (int n = 0; n < 4; ++n) {
                acc[m][n] = __builtin_amdgcn_mfma_f32_16x16x32_bf16(ah[m], bh[n], acc[m][n], 0, 0, 0);
                acc[m][n] = __builtin_amdgcn_mfma_f32_16x16x32_bf16(ah[m], bl[n], acc[m][n], 0, 0, 0);
                acc[m][n] = __builtin_amdgcn_mfma_f32_16x16x32_bf16(al[m], bh[n], acc[m][n], 0, 0, 0);
            }
    }

    float* s = stg[wv];
    int r8 = l >> 3, cg = l & 7;
#pragma unroll
    for (int m = 0; m < 4; ++m) {
#pragma unroll
        for (int n = 0; n < 4; ++n)
#pragma unroll
            for (int q = 0; q < 4; ++q)
                s[((l >> 4) * 4 + q) * 66 + n * 16 + (l & 15)] = acc[m][n][q];
#pragma unroll
        for (int it = 0; it < 2; ++it) {
            int row = it * 8 + r8;
            const float* sr = s + row * 66 + cg * 8;
            int colbase = wc + cg * 8;
            unsigned int u[4];
#pragma unroll
            for (int p = 0; p < 4; ++p) {
                float f0 = fmaxf(sr[2 * p] + b1[colbase + 2 * p], 0.0f);
                float f1 = fmaxf(sr[2 * p + 1] + b1[colbase + 2 * p + 1], 0.0f);
                u[p] = ((unsigned int)f2b(f1) << 16) | f2b(f0);
            }
            long R = grow + wr + m * 16 + row;
            *(uint4*)(hidp + R * HID + colbase) = make_uint4(u[0], u[1], u[2], u[3]);
        }
    }
}

// ---------------- w2pt: fragment-major split-bf16 of B[i][j], j=o*128+k ----------------
__global__ void w2pt_kernel(const float* __restrict__ w2, unsigned short* __restrict__ wh,
                            unsigned short* __restrict__ wl) {
    int id = blockIdx.x * 256 + threadIdx.x;  // id = j*64 + i, over NJ*64
    int i = id & 63, j = id >> 6;
    int o = j >> 7, k = j & 127;  // j = o*128 + k
    float v = w2[k * NIO + i * 64 + o];
    unsigned short hi = f2b(v);
    long idx = fidx64(j, i);  // "row"=j (panel dim), contraction k-dim = i
    wh[idx] = hi;
    wl[idx] = f2b(v - b2f(hi));
}

// ---------------- xb2[n,o] = sum_i x[n,i] * b2[i*64+o]  (f32, exact) ----------------
__global__ void xb2_kernel(const float* __restrict__ x, const float* __restrict__ b2,
                           float* __restrict__ xb2) {
    int wv = threadIdx.x >> 6, l = threadIdx.x & 63;
    int n = blockIdx.x * 4 + wv;
    float xv = x[n * NF + l];
    float acc = 0.0f;
#pragma unroll
    for (int i = 0; i < 64; ++i) acc += __shfl(xv, i) * b2[i * 64 + l];
    xb2[n * NF + l] = acc;
}

// ---------------- ygemm: y[r, j] = sum_i x[n0+r, i] * w2p[j, i]  (split 3-pass, coalesced frags) ----------------
__launch_bounds__(256)
__global__ void ygemm_kernel(const unsigned short* __restrict__ xh, const unsigned short* __restrict__ xl,
                             const unsigned short* __restrict__ wh, const unsigned short* __restrict__ wl,
                             unsigned short* __restrict__ y, int n0) {
    __shared__ float stg[4][1056];  // 16 rows x stride 66
    const int tid = threadIdx.x, wv = tid >> 6, l = tid & 63;
    const int grow = blockIdx.x * 128;  // chunk-local row base
    const int col0 = blockIdx.y * 128;  // in [0, NJ)
    const int wr = (wv >> 1) * 64, wc = (wv & 1) * 64;
    const long apan0 = ((n0 + grow + wr) >> 4);  // n0, grow, wr all 16-aligned
    const long bpan0 = ((col0 + wc) >> 4);

    f32x4 acc[4][4] = {};
#pragma unroll
    for (int ks = 0; ks < 2; ++ks) {
        bf16x8 ah[4], al[4], bh[4], bl[4];
#pragma unroll
        for (int m = 0; m < 4; ++m) {
            long o = (apan0 + m) * 1024 + ks * 512 + (long)l * 8;
            ah[m] = *(const bf16x8*)(xh + o);
            al[m] = *(const bf16x8*)(xl + o);
        }
#pragma unroll
        for (int n = 0; n < 4; ++n) {
            long o = (bpan0 + n) * 1024 + ks * 512 + (long)l * 8;
            bh[n] = *(const bf16x8*)(wh + o);
            bl[n] = *(const bf16x8*)(wl + o);
        }
#pragma unroll
        for (int m = 0; m < 4; ++m)
#pragma unroll
            for (int n = 0; n < 4; ++n) {
                acc[m][n] = __builtin_amdgcn_mfma_f32_16x16x32_bf16(ah[m], bh[n], acc[m][n], 0, 0, 0);
                acc[m][n] = __builtin_amdgcn_mfma_f32_16x16x32_bf16(ah[m], bl[n], acc[m][n], 0, 0, 0);
                acc[m][n] = __builtin_amdgcn_mfma_f32_16x16x32_bf16(al[m], bh[n], acc[m][n], 0, 0, 0);
            }
    }

    float* s = stg[wv];
    int r8 = l >> 3, cg = l & 7;
#pragma unroll
    for (int m = 0; m < 4; ++m) {
#pragma unroll
        for (int n = 0; n < 4; ++n)
#pragma unroll
            for (int q = 0; q < 4; ++q)
                s[((l >> 4) * 4 + q) * 66 + n * 16 + (l & 15)] = acc[m][n][q];
        // wave-private staging: same-wave ds_write -> ds_read ordered via lgkmcnt
#pragma unroll
        for (int it = 0; it < 2; ++it) {
            int row = it * 8 + r8;
            const float* sr = s + row * 66 + cg * 8;
            unsigned int u[4];
#pragma unroll
            for (int p = 0; p < 4; ++p)
                u[p] = ((unsigned int)f2b(sr[2 * p + 1]) << 16) | f2b(sr[2 * p]);
            long R = grow + wr + m * 16 + row;  // chunk-local
            *(uint4*)(y + R * NJ + col0 + wc + cg * 8) = make_uint4(u[0], u[1], u[2], u[3]);
        }
    }
}

// ---------------- per-node MFMA matvec: msg[d x 64] = H_s[d x 128] @ Y_s[128 x 64] ----------------
__global__ void matvec_mfma_kernel(const unsigned short* __restrict__ y,
                                   const unsigned short* __restrict__ hidp,
                                   const int* __restrict__ rowptr, const int* __restrict__ dstp,
                                   const float* __restrict__ xb2, float* __restrict__ agg,
                                   int n0) {
    int wv = threadIdx.x >> 6, l = threadIdx.x & 63;
    int s = n0 + blockIdx.x;
    int r0 = rowptr[s], r1 = rowptr[s + 1];
    if (r0 == r1) return;
    int co = wv * 16;              // o-quadrant base
    int lc = l & 15, lk = l >> 4;  // fragment col / k-group

    const unsigned short* Ys = y + (long)(s - n0) * NJ + (co + lc) * HID;
    bf16x8 b[4];
#pragma unroll
    for (int ks = 0; ks < 4; ++ks) b[ks] = *(const bf16x8*)(Ys + ks * 32 + lk * 8);
    float xb2v = xb2[(long)s * NF + co + lc];

    for (int mt = r0; mt < r1; mt += 16) {
        const unsigned short* Hs = hidp + (long)(mt + lc) * HID + lk * 8;
        f32x4 acc = {};
#pragma unroll
        for (int ks = 0; ks < 4; ++ks) {
            bf16x8 a = *(const bf16x8*)(Hs + ks * 32);  // rows beyond r1: pad garbage, discarded
            acc = __builtin_amdgcn_mfma_f32_16x16x32_bf16(a, b[ks], acc, 0, 0, 0);
        }
#pragma unroll
        for (int q = 0; q < 4; ++q) {
            int rank = mt + lk * 4 + q;  // C row = (l>>4)*4 + q
            if (rank < r1) {
                int dd = dstp[rank];
                atomicAdd(&agg[(long)dd * NF + co + lc], acc[q] + xb2v);
            }
        }
    }
}

// ---------------- x' = agg*inv_deg + x @ root_w + conv_b (+ optional fragment-major mirrors) ----------------
__global__ void combine_kernel(const float* __restrict__ x, const float* __restrict__ agg,
                               const float* __restrict__ invd, const float* __restrict__ rw,
                               const float* __restrict__ cb, float* __restrict__ xo,
                               unsigned short* __restrict__ xh, unsigned short* __restrict__ xl) {
    int wv = threadIdx.x >> 6, l = threadIdx.x & 63;
    int n = blockIdx.x * 4 + wv;
    float xv = x[n * NF + l];
    float acc = cb[l];
#pragma unroll
    for (int i = 0; i < 64; ++i) acc += __shfl(xv, i) * rw[i * NF + l];
    float v = agg[n * NF + l] * invd[n] + acc;
    xo[n * NF + l] = v;
    if (xh) {
        unsigned short hi = f2b(v);
        long idx = fidx64(n, l);
        xh[idx] = hi;
        xl[idx] = f2b(v - b2f(hi));
    }
}

extern "C" void kernel_launch(void* const* d_in, const int* in_sizes, int n_in,
                              void* d_out, int out_size, void* d_ws, size_t ws_size,
                              hipStream_t stream) {
    const float* h = (const float*)d_in[0];
    const int* ei = (const int*)d_in[1];  // int inputs arrive as int32
    const float* ea = (const float*)d_in[3];
    const float* lin0_w = (const float*)d_in[5];
    const float* lin0_b = (const float*)d_in[6];
    const float* nn_w1 = (const float*)d_in[7];
    const float* nn_b1 = (const float*)d_in[8];
    const float* nn_w2 = (const float*)d_in[9];
    const float* nn_b2 = (const float*)d_in[10];
    const float* root_w = (const float*)d_in[11];
    const float* conv_b = (const float*)d_in[12];
    const int* srcIdx = ei;
    const int* dstIdx = ei + N_EDGES;

    // ---- tier selection: chunk sizes 128-aligned (fragment panels need 16-aligned bases) ----
    const size_t eaBytes = (size_t)2 * N_EDGES * HID * 2;  // eah + eal (aliased with y)
    const size_t fixed =
        (size_t)(N_EDGES + 16) * HID * 2 +  // hidp (+16 pad rows)
        (size_t)NJ * NF * 2 * 2 +           // w2pt hi/lo
        (size_t)HID * HID * 2 * 2 +         // w1pt hi/lo
        (size_t)M_PAD * NF * 2 * 2 +        // x hi/lo fragment mirrors
        (size_t)N_NODES * NF * 4 * 4 +      // xA, xB, agg, xb2
        (size_t)N_NODES * 4 * 4 +           // deg, invd, cnt, fill
        (size_t)(N_NODES + 1) * 4 +         // rowptr
        (size_t)N_EDGES * 4 * 3 +           // rankOf, dstp, edgeOf
        32768;                              // alignment slack
    int nc = 0, CSn = 0;
    size_t region_bytes = 0;
    for (int c = 1; c <= 16; c *= 2) {
        int csn = (((N_NODES + c - 1) / c) + 127) & ~127;  // 128-aligned chunk size
        size_t rb = (size_t)csn * NJ * 2;
        if (rb < eaBytes) rb = eaBytes;
        if (fixed + rb <= ws_size) { nc = c; CSn = csn; region_bytes = rb; break; }
    }
    if (nc == 0) {
        hipMemsetAsync(d_out, 0, (size_t)out_size * 4, stream);
        return;
    }

    char* ws = (char*)d_ws;
    size_t off = 0;
    auto alloc = [&](size_t bytes) {
        char* p = ws + off;
        off += (bytes + 255) & ~(size_t)255;
        return p;
    };
    unsigned short* region = (unsigned short*)alloc(region_bytes);
    unsigned short* y = region;                     // conv loop
    unsigned short* eah = region;                   // prep only (consumed by hgemm)
    unsigned short* eal = region + (size_t)N_EDGES * HID;
    unsigned short* hidp = (unsigned short*)alloc((size_t)(N_EDGES + 16) * HID * 2);
    unsigned short* w2h = (unsigned short*)alloc((size_t)NJ * NF * 2);
    unsigned short* w2l = (unsigned short*)alloc((size_t)NJ * NF * 2);
    unsigned short* w1h = (unsigned short*)alloc((size_t)HID * HID * 2);
    unsigned short* w1l = (unsigned short*)alloc((size_t)HID * HID * 2);
    unsigned short* xh = (unsigned short*)alloc((size_t)M_PAD * NF * 2);
    unsigned short* xl = (unsigned short*)alloc((size_t)M_PAD * NF * 2);
    float* xA = (float*)alloc((size_t)N_NODES * NF * 4);
    float* xB = (float*)alloc((size_t)N_NODES * NF * 4);
    float* agg = (float*)alloc((size_t)N_NODES * NF * 4);
    float* xb2 = (float*)alloc((size_t)N_NODES * NF * 4);
    float* deg = (float*)alloc((size_t)N_NODES * 4);
    float* invd = (float*)alloc((size_t)N_NODES * 4);
    int* cnt = (int*)alloc((size_t)N_NODES * 4);
    int* fill = (int*)alloc((size_t)N_NODES * 4);
    int* rowptr = (int*)alloc((size_t)(N_NODES + 1) * 4);
    int* rankOf = (int*)alloc((size_t)N_EDGES * 4);
    int* dstp = (int*)alloc((size_t)N_EDGES * 4);
    int* edgeOf = (int*)alloc((size_t)N_EDGES * 4);

    // ---- CSR by src + prep ----
    hipMemsetAsync(deg, 0, (size_t)N_NODES * 4, stream);
    hipMemsetAsync(cnt, 0, (size_t)N_NODES * 4, stream);
    hipMemsetAsync(fill, 0, (size_t)N_NODES * 4, stream);
    hist_kernel<<<(N_EDGES + 255) / 256, 256, 0, stream>>>(srcIdx, dstIdx, deg, cnt);
    invdeg_kernel<<<(N_NODES + 255) / 256, 256, 0, stream>>>(deg, invd);
    scan_kernel<<<1, 256, 0, stream>>>(cnt, rowptr);
    scatter_kernel<<<(N_EDGES + 255) / 256, 256, 0, stream>>>(srcIdx, dstIdx, rowptr, fill, rankOf, dstp, edgeOf);
    lin0_kernel<<<N_NODES / 4, 256, 0, stream>>>(h, lin0_w, lin0_b, xA, xh, xl);
    eaperm_kernel<<<N_EDGES / 16, 256, 0, stream>>>(ea, edgeOf, eah, eal);
    w1pt_kernel<<<(HID * HID) / 256, 256, 0, stream>>>(nn_w1, w1h, w1l);
    hgemm_kernel<<<N_EDGES / 128, 256, 0, stream>>>(eah, eal, w1h, w1l, nn_b1, hidp);  // consumes ea region
    w2pt_kernel<<<(NJ * NF) / 256, 256, 0, stream>>>(nn_w2, w2h, w2l);

    // ---- two conv applications (shared weights) ----
    for (int conv = 0; conv < 2; ++conv) {
        const float* xin = conv ? xB : xA;
        float* xout = conv ? (float*)d_out : xB;
        unsigned short* mh = conv ? nullptr : xh;
        unsigned short* ml = conv ? nullptr : xl;

        xb2_kernel<<<N_NODES / 4, 256, 0, stream>>>(xin, nn_b2, xb2);
        hipMemsetAsync(agg, 0, (size_t)N_NODES * NF * 4, stream);
        for (int c = 0; c < nc; ++c) {
            int n0 = c * CSn;
            int n1 = n0 + CSn; if (n1 > N_NODES) n1 = N_NODES;
            if (n0 >= N_NODES) break;
            int gx = (n1 - n0 + 127) / 128;
            ygemm_kernel<<<dim3(gx, NJ / 128), 256, 0, stream>>>(xh, xl, w2h, w2l, y, n0);
            matvec_mfma_kernel<<<n1 - n0, 256, 0, stream>>>(y, hidp, rowptr, dstp, xb2, agg, n0);
        }
        combine_kernel<<<N_NODES / 4, 256, 0, stream>>>(xin, agg, invd, root_w, conv_b, xout, mh, ml);
    }
}

// Round 9
// 416.692 us; speedup vs baseline: 3.5809x; 1.0548x over previous
//
#include <hip/hip_runtime.h>

#define N_NODES 10000
#define N_EDGES 160000
#define HID 128
#define NG 100
#define NF 64
#define NIO 4096     // NF*NF (w2 row stride)
#define NJ 8192      // permuted columns: o(64) x k(128), o-major
#define M_PAD 10240  // padded x rows (chunked GEMM may read past N_NODES)

typedef short bf16x8 __attribute__((ext_vector_type(8)));
typedef float f32x4 __attribute__((ext_vector_type(4)));

__device__ __forceinline__ unsigned short f2b(float f) {
    unsigned int u = __float_as_uint(f);
    u += 0x7fffu + ((u >> 16) & 1u);  // RNE
    return (unsigned short)(u >> 16);
}
__device__ __forceinline__ float b2f(unsigned short s) { return __uint_as_float((unsigned int)s << 16); }

// fragment-major index helpers: element (row, k) of a K=64 operand matrix
// layout: [panel=row>>4][ks=k>>5][slot=((k>>3)&3)*16 + (row&15)][k&7], panel stride 1024
__device__ __forceinline__ long fidx64(int row, int k) {
    return (long)(row >> 4) * 1024 + (k >> 5) * 512 + ((((k >> 3) & 3) * 16 + (row & 15))) * 8 + (k & 7);
}
// K=128 operand matrix, panel stride 2048
__device__ __forceinline__ long fidx128(int row, int k) {
    return (long)(row >> 4) * 2048 + (k >> 5) * 512 + ((((k >> 3) & 3) * 16 + (row & 15))) * 8 + (k & 7);
}

// ---------------- histograms (dst-degree for mean; src-count for CSR) ----------------
__global__ void hist_kernel(const int* __restrict__ src, const int* __restrict__ dst,
                            float* __restrict__ deg, int* __restrict__ cnt) {
    int e = blockIdx.x * 256 + threadIdx.x;
    if (e < N_EDGES) {
        atomicAdd(&deg[dst[e]], 1.0f);
        atomicAdd(&cnt[src[e]], 1);
    }
}

// ---------------- single-pass scan: rowptr = excl-prefix(cnt); also invd = 1/max(deg,1) ----------------
#define SCAN_C 40  // 256 threads x 40 = 10240 >= N_NODES
__global__ void scan_kernel(const int* __restrict__ cnt, const float* __restrict__ deg,
                            int* __restrict__ rowptr, float* __restrict__ invd) {
    __shared__ int wsum[4];
    int t = threadIdx.x, wv = t >> 6, l = t & 63;
    int base_i = t * SCAN_C;
    int loc[SCAN_C];
    int sum = 0;
#pragma unroll
    for (int j = 0; j < SCAN_C; ++j) {
        int g = base_i + j;
        int v = (g < N_NODES) ? cnt[g] : 0;
        loc[j] = sum;  // exclusive prefix within thread
        sum += v;
    }
    int incl = sum;
    for (int off = 1; off < 64; off <<= 1) {
        int v = __shfl_up(incl, off);
        if (l >= off) incl += v;
    }
    if (l == 63) wsum[wv] = incl;
    __syncthreads();
    int wbase = 0;
#pragma unroll
    for (int w = 0; w < 4; ++w) wbase += (w < wv) ? wsum[w] : 0;
    int tbase = wbase + incl - sum;  // exclusive across block
#pragma unroll
    for (int j = 0; j < SCAN_C; ++j) {
        int g = base_i + j;
        if (g <= N_NODES) rowptr[g] = tbase + loc[j];
        if (g < N_NODES) invd[g] = 1.0f / fmaxf(deg[g], 1.0f);
    }
}

// ---------------- scatter: rankOf[e], dstp[rank], edgeOf[rank] ----------------
__global__ void scatter_kernel(const int* __restrict__ src, const int* __restrict__ dst,
                               const int* __restrict__ rowptr, int* __restrict__ fill,
                               int* __restrict__ rankOf, int* __restrict__ dstp,
                               int* __restrict__ edgeOf) {
    int e = blockIdx.x * 256 + threadIdx.x;
    if (e < N_EDGES) {
        int s = src[e];
        int r = rowptr[s] + atomicAdd(&fill[s], 1);
        rankOf[e] = r;
        dstp[r] = dst[e];
        edgeOf[r] = e;
    }
}

// ---------------- x0 = relu(h @ lin0_w + b); f32 + frag mirrors + fused xb2 ----------------
__global__ void lin0_kernel(const float* __restrict__ h, const float* __restrict__ w,
                            const float* __restrict__ b, const float* __restrict__ b2,
                            float* __restrict__ x, unsigned short* __restrict__ xh,
                            unsigned short* __restrict__ xl, float* __restrict__ xb2) {
    int wv = threadIdx.x >> 6, l = threadIdx.x & 63;
    int n = blockIdx.x * 4 + wv;
    float h0 = h[n * HID + l];
    float h1 = h[n * HID + 64 + l];
    float acc = b[l];
#pragma unroll
    for (int i = 0; i < 64; ++i) {
        acc += __shfl(h0, i) * w[i * NF + l];
        acc += __shfl(h1, i) * w[(64 + i) * NF + l];
    }
    float v = fmaxf(acc, 0.0f);
    x[n * NF + l] = v;
    unsigned short hi = f2b(v);
    long idx = fidx64(n, l);
    xh[idx] = hi;
    xl[idx] = f2b(v - b2f(hi));
    float xb = 0.0f;
#pragma unroll
    for (int i = 0; i < 64; ++i) xb += __shfl(v, i) * b2[i * 64 + l];
    xb2[n * NF + l] = xb;
}

// ---------------- eaperm: ea rows -> rank order, split-bf16, fragment-major (K pad 128) ----------------
__global__ void eaperm_kernel(const float* __restrict__ ea, const int* __restrict__ edgeOf,
                              unsigned short* __restrict__ eah, unsigned short* __restrict__ eal) {
    int t = threadIdx.x;
    int r15 = t & 15, ksl = t >> 4;  // ksl in [0,16)
    int ks = ksl >> 2, lk = ksl & 3;
    long rank = (long)blockIdx.x * 16 + r15;
    long e = edgeOf[rank];
    int c0 = ks * 32 + lk * 8;
    unsigned int uh[4], ul[4];
#pragma unroll
    for (int p = 0; p < 4; ++p) {
        float v0 = (c0 + 2 * p < NG) ? ea[e * NG + c0 + 2 * p] : 0.0f;
        float v1 = (c0 + 2 * p + 1 < NG) ? ea[e * NG + c0 + 2 * p + 1] : 0.0f;
        unsigned short h0 = f2b(v0), h1 = f2b(v1);
        uh[p] = ((unsigned int)h1 << 16) | h0;
        unsigned short l0 = f2b(v0 - b2f(h0)), l1 = f2b(v1 - b2f(h1));
        ul[p] = ((unsigned int)l1 << 16) | l0;
    }
    long idx = (long)blockIdx.x * 2048 + ks * 512 + (lk * 16 + r15) * 8;
    *(uint4*)(eah + idx) = make_uint4(uh[0], uh[1], uh[2], uh[3]);
    *(uint4*)(eal + idx) = make_uint4(ul[0], ul[1], ul[2], ul[3]);
}

// ---------------- merged weight permute: w1 (first 16384 ids) + w2 (rest) ----------------
__global__ void wpt_kernel(const float* __restrict__ w1, const float* __restrict__ w2,
                           unsigned short* __restrict__ w1h, unsigned short* __restrict__ w1l,
                           unsigned short* __restrict__ w2h, unsigned short* __restrict__ w2l) {
    int id = blockIdx.x * 256 + threadIdx.x;
    if (id < HID * HID) {  // w1: k = id&127, c = id>>7
        int k = id & 127, c = id >> 7;
        float v = (k < NG) ? w1[k * HID + c] : 0.0f;
        unsigned short hi = f2b(v);
        long idx = fidx128(c, k);
        w1h[idx] = hi;
        w1l[idx] = f2b(v - b2f(hi));
    } else {
        int id2 = id - HID * HID;  // id2 = j*64 + i, over NJ*64
        int i = id2 & 63, j = id2 >> 6;
        int o = j >> 7, k = j & 127;  // j = o*128 + k
        float v = w2[k * NIO + i * 64 + o];
        unsigned short hi = f2b(v);
        long idx = fidx64(j, i);
        w2h[idx] = hi;
        w2l[idx] = f2b(v - b2f(hi));
    }
}

// ---------------- hgemm: hidp = relu(eap @ w1 + b1), M=NE N=128 K=128, split 3-pass ----------------
__launch_bounds__(256)
__global__ void hgemm_kernel(const unsigned short* __restrict__ eah, const unsigned short* __restrict__ eal,
                             const unsigned short* __restrict__ w1h, const unsigned short* __restrict__ w1l,
                             const float* __restrict__ b1, unsigned short* __restrict__ hidp) {
    __shared__ float stg[4][1056];  // 16 rows x stride 66
    const int tid = threadIdx.x, wv = tid >> 6, l = tid & 63;
    const long grow = (long)blockIdx.x * 128;
    const int wr = (wv >> 1) * 64, wc = (wv & 1) * 64;
    const long apan0 = (grow >> 4) + (wr >> 4);
    const long bpan0 = (wc >> 4);

    f32x4 acc[4][4] = {};
#pragma unroll
    for (int ks = 0; ks < 4; ++ks) {
        bf16x8 ah[4], al[4], bh[4], bl[4];
#pragma unroll
        for (int m = 0; m < 4; ++m) {
            long o = (apan0 + m) * 2048 + ks * 512 + (long)l * 8;
            ah[m] = *(const bf16x8*)(eah + o);
            al[m] = *(const bf16x8*)(eal + o);
        }
#pragma unroll
        for (int n = 0; n < 4; ++n) {
            long o = (bpan0 + n) * 2048 + ks * 512 + (long)l * 8;
            bh[n] = *(const bf16x8*)(w1h + o);
            bl[n] = *(const bf16x8*)(w1l + o);
        }
#pragma unroll
        for (int m = 0; m < 4; ++m)
#pragma unroll
            for (int n = 0; n < 4; ++n) {
                acc[m][n] = __builtin_amdgcn_mfma_f32_16x16x32_bf16(ah[m], bh[n], acc[m][n], 0, 0, 0);
                acc[m][n] = __builtin_amdgcn_mfma_f32_16x16x32_bf16(ah[m], bl[n], acc[m][n], 0, 0, 0);
                acc[m][n] = __builtin_amdgcn_mfma_f32_16x16x32_bf16(al[m], bh[n], acc[m][n], 0, 0, 0);
            }
    }

    float* s = stg[wv];
    int r8 = l >> 3, cg = l & 7;
#pragma unroll
    for (int m = 0; m < 4; ++m) {
#pragma unroll
        for (int n = 0; n < 4; ++n)
#pragma unroll
            for (int q = 0; q < 4; ++q)
                s[((l >> 4) * 4 + q) * 66 + n * 16 + (l & 15)] = acc[m][n][q];
#pragma unroll
        for (int it = 0; it < 2; ++it) {
            int row = it * 8 + r8;
            const float* sr = s + row * 66 + cg * 8;
            int colbase = wc + cg * 8;
            unsigned int u[4];
#pragma unroll
            for (int p = 0; p < 4; ++p) {
                float f0 = fmaxf(sr[2 * p] + b1[colbase + 2 * p], 0.0f);
                float f1 = fmaxf(sr[2 * p + 1] + b1[colbase + 2 * p + 1], 0.0f);
                u[p] = ((unsigned int)f2b(f1) << 16) | f2b(f0);
            }
            long R = grow + wr + m * 16 + row;
            *(uint4*)(hidp + R * HID + colbase) = make_uint4(u[0], u[1], u[2], u[3]);
        }
    }
}

// ---------------- ygemm: y[r, j] = sum_i x[n0+r, i] * w2p[j, i]  (split 3-pass, coalesced frags) ----------------
__launch_bounds__(256)
__global__ void ygemm_kernel(const unsigned short* __restrict__ xh, const unsigned short* __restrict__ xl,
                             const unsigned short* __restrict__ wh, const unsigned short* __restrict__ wl,
                             unsigned short* __restrict__ y, int n0) {
    __shared__ float stg[4][1056];  // 16 rows x stride 66
    const int tid = threadIdx.x, wv = tid >> 6, l = tid & 63;
    const int grow = blockIdx.x * 128;  // chunk-local row base
    const int col0 = blockIdx.y * 128;  // in [0, NJ)
    const int wr = (wv >> 1) * 64, wc = (wv & 1) * 64;
    const long apan0 = ((n0 + grow + wr) >> 4);  // n0, grow, wr all 16-aligned
    const long bpan0 = ((col0 + wc) >> 4);

    f32x4 acc[4][4] = {};
#pragma unroll
    for (int ks = 0; ks < 2; ++ks) {
        bf16x8 ah[4], al[4], bh[4], bl[4];
#pragma unroll
        for (int m = 0; m < 4; ++m) {
            long o = (apan0 + m) * 1024 + ks * 512 + (long)l * 8;
            ah[m] = *(const bf16x8*)(xh + o);
            al[m] = *(const bf16x8*)(xl + o);
        }
#pragma unroll
        for (int n = 0; n < 4; ++n) {
            long o = (bpan0 + n) * 1024 + ks * 512 + (long)l * 8;
            bh[n] = *(const bf16x8*)(wh + o);
            bl[n] = *(const bf16x8*)(wl + o);
        }
#pragma unroll
        for (int m = 0; m < 4; ++m)
#pragma unroll
            for (int n = 0; n < 4; ++n) {
                acc[m][n] = __builtin_amdgcn_mfma_f32_16x16x32_bf16(ah[m], bh[n], acc[m][n], 0, 0, 0);
                acc[m][n] = __builtin_amdgcn_mfma_f32_16x16x32_bf16(ah[m], bl[n], acc[m][n], 0, 0, 0);
                acc[m][n] = __builtin_amdgcn_mfma_f32_16x16x32_bf16(al[m], bh[n], acc[m][n], 0, 0, 0);
            }
    }

    float* s = stg[wv];
    int r8 = l >> 3, cg = l & 7;
#pragma unroll
    for (int m = 0; m < 4; ++m) {
#pragma unroll
        for (int n = 0; n < 4; ++n)
#pragma unroll
            for (int q = 0; q < 4; ++q)
                s[((l >> 4) * 4 + q) * 66 + n * 16 + (l & 15)] = acc[m][n][q];
        // wave-private staging: same-wave ds_write -> ds_read ordered via lgkmcnt
#pragma unroll
        for (int it = 0; it < 2; ++it) {
            int row = it * 8 + r8;
            const float* sr = s + row * 66 + cg * 8;
            unsigned int u[4];
#pragma unroll
            for (int p = 0; p < 4; ++p)
                u[p] = ((unsigned int)f2b(sr[2 * p + 1]) << 16) | f2b(sr[2 * p]);
            long R = grow + wr + m * 16 + row;  // chunk-local
            *(uint4*)(y + R * NJ + col0 + wc + cg * 8) = make_uint4(u[0], u[1], u[2], u[3]);
        }
    }
}

// ---------------- per-node MFMA matvec: msg[d x 64] = H_s[d x 128] @ Y_s[128 x 64] ----------------
__global__ void matvec_mfma_kernel(const unsigned short* __restrict__ y,
                                   const unsigned short* __restrict__ hidp,
                                   const int* __restrict__ rowptr, const int* __restrict__ dstp,
                                   const float* __restrict__ xb2, float* __restrict__ agg,
                                   int n0) {
    int wv = threadIdx.x >> 6, l = threadIdx.x & 63;
    int s = n0 + blockIdx.x;
    int r0 = rowptr[s], r1 = rowptr[s + 1];
    if (r0 == r1) return;
    int co = wv * 16;              // o-quadrant base
    int lc = l & 15, lk = l >> 4;  // fragment col / k-group

    const unsigned short* Ys = y + (long)(s - n0) * NJ + (co + lc) * HID;
    bf16x8 b[4];
#pragma unroll
    for (int ks = 0; ks < 4; ++ks) b[ks] = *(const bf16x8*)(Ys + ks * 32 + lk * 8);
    float xb2v = xb2[(long)s * NF + co + lc];

    for (int mt = r0; mt < r1; mt += 16) {
        const unsigned short* Hs = hidp + (long)(mt + lc) * HID + lk * 8;
        f32x4 acc = {};
#pragma unroll
        for (int ks = 0; ks < 4; ++ks) {
            bf16x8 a = *(const bf16x8*)(Hs + ks * 32);  // rows beyond r1: pad garbage, discarded
            acc = __builtin_amdgcn_mfma_f32_16x16x32_bf16(a, b[ks], acc, 0, 0, 0);
        }
#pragma unroll
        for (int q = 0; q < 4; ++q) {
            int rank = mt + lk * 4 + q;  // C row = (l>>4)*4 + q
            if (rank < r1) {
                int dd = dstp[rank];
                atomicAdd(&agg[(long)dd * NF + co + lc], acc[q] + xb2v);
            }
        }
    }
}

// ---------------- x' = agg*inv_deg + x @ root_w + conv_b (+ conv0: mirrors & next xb2) ----------------
__global__ void combine_kernel(const float* __restrict__ x, const float* __restrict__ agg,
                               const float* __restrict__ invd, const float* __restrict__ rw,
                               const float* __restrict__ cb, const float* __restrict__ b2,
                               float* __restrict__ xo, unsigned short* __restrict__ xh,
                               unsigned short* __restrict__ xl, float* __restrict__ xb2) {
    int wv = threadIdx.x >> 6, l = threadIdx.x & 63;
    int n = blockIdx.x * 4 + wv;
    float xv = x[n * NF + l];
    float acc = cb[l];
#pragma unroll
    for (int i = 0; i < 64; ++i) acc += __shfl(xv, i) * rw[i * NF + l];
    float v = agg[n * NF + l] * invd[n] + acc;
    xo[n * NF + l] = v;
    if (xh) {
        unsigned short hi = f2b(v);
        long idx = fidx64(n, l);
        xh[idx] = hi;
        xl[idx] = f2b(v - b2f(hi));
        float xb = 0.0f;
#pragma unroll
        for (int i = 0; i < 64; ++i) xb += __shfl(v, i) * b2[i * 64 + l];
        xb2[n * NF + l] = xb;
    }
}

extern "C" void kernel_launch(void* const* d_in, const int* in_sizes, int n_in,
                              void* d_out, int out_size, void* d_ws, size_t ws_size,
                              hipStream_t stream) {
    const float* h = (const float*)d_in[0];
    const int* ei = (const int*)d_in[1];  // int inputs arrive as int32
    const float* ea = (const float*)d_in[3];
    const float* lin0_w = (const float*)d_in[5];
    const float* lin0_b = (const float*)d_in[6];
    const float* nn_w1 = (const float*)d_in[7];
    const float* nn_b1 = (const float*)d_in[8];
    const float* nn_w2 = (const float*)d_in[9];
    const float* nn_b2 = (const float*)d_in[10];
    const float* root_w = (const float*)d_in[11];
    const float* conv_b = (const float*)d_in[12];
    const int* srcIdx = ei;
    const int* dstIdx = ei + N_EDGES;

    // ---- tier selection: chunk sizes 128-aligned (fragment panels need 16-aligned bases) ----
    const size_t eaBytes = (size_t)2 * N_EDGES * HID * 2;  // eah + eal (aliased with y)
    const size_t fixed =
        (size_t)(N_EDGES + 16) * HID * 2 +  // hidp (+16 pad rows)
        (size_t)NJ * NF * 2 * 2 +           // w2pt hi/lo
        (size_t)HID * HID * 2 * 2 +         // w1pt hi/lo
        (size_t)M_PAD * NF * 2 * 2 +        // x hi/lo fragment mirrors
        (size_t)N_NODES * NF * 4 * 4 +      // xA, xB, agg, xb2
        4 * 40192 +                         // deg/invd/cnt/fill block
        (size_t)(N_NODES + 1) * 4 +         // rowptr
        (size_t)N_EDGES * 4 * 3 +           // rankOf, dstp, edgeOf
        32768;                              // alignment slack
    int nc = 0, CSn = 0;
    size_t region_bytes = 0;
    for (int c = 1; c <= 16; c *= 2) {
        int csn = (((N_NODES + c - 1) / c) + 127) & ~127;  // 128-aligned chunk size
        size_t rb = (size_t)csn * NJ * 2;
        if (rb < eaBytes) rb = eaBytes;
        if (fixed + rb <= ws_size) { nc = c; CSn = csn; region_bytes = rb; break; }
    }
    if (nc == 0) {
        hipMemsetAsync(d_out, 0, (size_t)out_size * 4, stream);
        return;
    }

    char* ws = (char*)d_ws;
    size_t off = 0;
    auto alloc = [&](size_t bytes) {
        char* p = ws + off;
        off += (bytes + 255) & ~(size_t)255;
        return p;
    };
    unsigned short* region = (unsigned short*)alloc(region_bytes);
    unsigned short* y = region;                     // conv loop
    unsigned short* eah = region;                   // prep only (consumed by hgemm)
    unsigned short* eal = region + (size_t)N_EDGES * HID;
    unsigned short* hidp = (unsigned short*)alloc((size_t)(N_EDGES + 16) * HID * 2);
    unsigned short* w2h = (unsigned short*)alloc((size_t)NJ * NF * 2);
    unsigned short* w2l = (unsigned short*)alloc((size_t)NJ * NF * 2);
    unsigned short* w1h = (unsigned short*)alloc((size_t)HID * HID * 2);
    unsigned short* w1l = (unsigned short*)alloc((size_t)HID * HID * 2);
    unsigned short* xh = (unsigned short*)alloc((size_t)M_PAD * NF * 2);
    unsigned short* xl = (unsigned short*)alloc((size_t)M_PAD * NF * 2);
    float* xA = (float*)alloc((size_t)N_NODES * NF * 4);
    float* xB = (float*)alloc((size_t)N_NODES * NF * 4);
    float* agg = (float*)alloc((size_t)N_NODES * NF * 4);
    float* xb2 = (float*)alloc((size_t)N_NODES * NF * 4);
    char* degblk = alloc(4 * 40192);                // deg | invd | cnt | fill (one memset)
    float* deg = (float*)degblk;
    float* invd = (float*)(degblk + 40192);
    int* cnt = (int*)(degblk + 2 * 40192);
    int* fill = (int*)(degblk + 3 * 40192);
    int* rowptr = (int*)alloc((size_t)(N_NODES + 1) * 4);
    int* rankOf = (int*)alloc((size_t)N_EDGES * 4);
    int* dstp = (int*)alloc((size_t)N_EDGES * 4);
    int* edgeOf = (int*)alloc((size_t)N_EDGES * 4);

    // ---- CSR by src + prep ----
    hipMemsetAsync(degblk, 0, 4 * 40192, stream);
    hist_kernel<<<(N_EDGES + 255) / 256, 256, 0, stream>>>(srcIdx, dstIdx, deg, cnt);
    scan_kernel<<<1, 256, 0, stream>>>(cnt, deg, rowptr, invd);
    scatter_kernel<<<(N_EDGES + 255) / 256, 256, 0, stream>>>(srcIdx, dstIdx, rowptr, fill, rankOf, dstp, edgeOf);
    lin0_kernel<<<N_NODES / 4, 256, 0, stream>>>(h, lin0_w, lin0_b, nn_b2, xA, xh, xl, xb2);
    eaperm_kernel<<<N_EDGES / 16, 256, 0, stream>>>(ea, edgeOf, eah, eal);
    wpt_kernel<<<(HID * HID + NJ * NF) / 256, 256, 0, stream>>>(nn_w1, nn_w2, w1h, w1l, w2h, w2l);
    hgemm_kernel<<<N_EDGES / 128, 256, 0, stream>>>(eah, eal, w1h, w1l, nn_b1, hidp);  // consumes ea region

    // ---- two conv applications (shared weights) ----
    for (int conv = 0; conv < 2; ++conv) {
        const float* xin = conv ? xB : xA;
        float* xout = conv ? (float*)d_out : xB;
        unsigned short* mh = conv ? nullptr : xh;
        unsigned short* ml = conv ? nullptr : xl;

        hipMemsetAsync(agg, 0, (size_t)N_NODES * NF * 4, stream);
        for (int c = 0; c < nc; ++c) {
            int n0 = c * CSn;
            int n1 = n0 + CSn; if (n1 > N_NODES) n1 = N_NODES;
            if (n0 >= N_NODES) break;
            int gx = (n1 - n0 + 127) / 128;
            ygemm_kernel<<<dim3(gx, NJ / 128), 256, 0, stream>>>(xh, xl, w2h, w2l, y, n0);
            matvec_mfma_kernel<<<n1 - n0, 256, 0, stream>>>(y, hidp, rowptr, dstp, xb2, agg, n0);
        }
        // conv0's combine also produces conv1's mirrors and xb2 (xb2 consumed before overwrite)
        combine_kernel<<<N_NODES / 4, 256, 0, stream>>>(xin, agg, invd, root_w, conv_b, nn_b2,
                                                        xout, mh, ml, xb2);
    }
}